// Round 3
// baseline (328.080 us; speedup 1.0000x reference)
//
#include <hip/hip_runtime.h>
#include <math.h>

#define BB 2
#define NF 20000
#define NS 30000
#define CH 128
#define NK 500
#define KNN 16
#define KPB 4

// grid params: cell = 1.001 * radius (margin vs float boundary rounding)
#define HA 2.4024f
#define HB 4.8048f
#define NCA 45
#define NCB 23
#define CELLS_A 2025
#define CELLS_B 529

// multi-block counting sort for the spatial grid
#define GB 8                 // count/scatter blocks per (s,b)
#define SLICE 3750           // NS / GB points per block
#define SLICE4 1875          // int4 (2-point) loads per slice

// top-k decomposition
#define TKB 8                // collect blocks per batch
#define TSLICE 2500          // NF / TKB keys per block

// output offsets (floats, concatenated in return order)
#define OUT0_OFF 0           // out          (B*NK*128) = 128000
#define OUT1_OFF 128000      // key_voxel_indices (B*NK*3) = 3000
#define OUT2_OFF 131000      // heat_scores  (B*NF) = 40000
#define OUT3_OFF 171000      // scores10     (B*NF*10) = 400000
#define OUT4_OFF 571000      // key_class    (B*NK) = 1000

// workspace offsets (bytes)
#define WS_CLS   0           // int32  x 40000
#define WS_TKI   160000      // int32  x 1000
#define WS_KW    164000      // float  x 2000
#define WS_MF    172000      // float  x 256000 (1,024,000 B)
#define WS_KEYS  WS_MF       // u64 x 40000 overlays mf head (temporally disjoint)
#define WS_BH    492000      // int x 65536: per-block hists [sb][g][2048], overlays mf
#define WS_HIST  754144      // u32 x 32768: global topk hist [b][16384], overlays mf
#define WS_DONE  885216      // u32 x 2
#define WS_CCNT  885224      // u32 x 2
#define WS_CAND  885232      // u64 x 2048: candidate buffer [b][1024], overlays mf
#define WS_GSTART 1196000    // int x 5112 (cell starts, +1 per (s,b))
#define WS_PTS    1236880    // float2 x 120000 (sorted world coords)
#define WS_PIDX   2196880    // int x 120000 (sorted original indices)

#define STB(s,b)  ((s) ? (4052 + (b) * 530) : ((b) * 2026))

__device__ __forceinline__ void fma4(float4& acc, float sc, const float4& wv) {
    acc.x += sc * wv.x; acc.y += sc * wv.y;
    acc.z += sc * wv.z; acc.w += sc * wv.w;
}

__device__ __forceinline__ unsigned ordf(float s) {
    unsigned u = __float_as_uint(s);
    return (u & 0x80000000u) ? ~u : (u | 0x80000000u);
}

// identical arithmetic in count and scatter phases (bitwise-consistent cells)
__device__ __forceinline__ int cell_of(int cxi, int cyi, float stride, float inv_h,
                                       int nc, float& sx, float& sy)
{
    sx = __fadd_rn(__fmul_rn(__fmul_rn(__fadd_rn((float)cxi, 0.5f), stride), 0.075f), -54.0f);
    sy = __fadd_rn(__fmul_rn(__fmul_rn(__fadd_rn((float)cyi, 0.5f), stride), 0.075f), -54.0f);
    int cx = (int)floorf((sx + 54.0f) * inv_h);
    int cy = (int)floorf((sy + 54.0f) * inv_h);
    cx = min(max(cx, 0), nc - 1);
    cy = min(max(cy, 0), nc - 1);
    return cy * nc + cx;
}

// ---------------------------------------------------------------------------
// K1: blocks 0-31 = grid COUNT phase (8 blocks per (s,b), private per-block
// histograms); blocks 32+ = heat MLP SGEMM. Epilogue now also accumulates the
// global 14-bit top-k histogram (hist pre-zeroed by a memset node), so the
// top-k kernel never has to build it.
// ---------------------------------------------------------------------------
__global__ __launch_bounds__(256) void heat_kernel(
    const float* __restrict__ x,
    const float* __restrict__ w1,
    const float* __restrict__ g1, const float* __restrict__ b1,
    const float* __restrict__ w2,
    const float* __restrict__ b2,
    float* __restrict__ out_heat,
    float* __restrict__ out_s10,
    int* __restrict__ cls,
    unsigned long long* __restrict__ keys,
    const int* __restrict__ sca, const int* __restrict__ scb,
    int* __restrict__ bh,
    unsigned* __restrict__ hist)
{
    __shared__ float As[64 * 72];
    __shared__ float Ws[64 * 132];
    __shared__ float W2s[1280];
    const int tid = threadIdx.x;

    if (blockIdx.x < 4 * GB) {
        const int gflat = blockIdx.x;
        const int sb = gflat >> 3;          // 0..3
        const int gg = gflat & (GB - 1);    // 0..7
        const int s = sb >> 1, b = sb & 1;
        const float stride = s ? 8.0f : 4.0f;
        const float inv_h = s ? (1.0f / HB) : (1.0f / HA);
        const int nc = s ? NCB : NCA;
        const int2* sc = ((const int2*)(s ? scb : sca)) + (size_t)b * NS;
        const int4* scv = (const int4*)sc;
        int* hist_l = (int*)As;             // 2048 ints

        for (int i = tid; i < 2048; i += 256) hist_l[i] = 0;
        __syncthreads();
        for (int p = gg * SLICE4 + tid; p < (gg + 1) * SLICE4; p += 256) {
            int4 v = scv[p];
            float sx, sy;
            int cell0 = cell_of(v.x, v.y, stride, inv_h, nc, sx, sy);
            int cell1 = cell_of(v.z, v.w, stride, inv_h, nc, sx, sy);
            atomicAdd(&hist_l[cell0], 1);
            atomicAdd(&hist_l[cell1], 1);
        }
        __syncthreads();
        int* bhp = bh + (gflat << 11);
        for (int i = tid; i < 2048; i += 256) bhp[i] = hist_l[i];
        return;
    }

    const int m0 = (blockIdx.x - 4 * GB) * 64;
    const int tx = tid & 15;
    const int ty = tid >> 4;

    for (int v = tid; v < 1280; v += 256) W2s[v] = w2[v];

    float acc[4][8];
#pragma unroll
    for (int i = 0; i < 4; ++i)
#pragma unroll
        for (int j = 0; j < 8; ++j) acc[i][j] = 0.f;

    const float4* xv = (const float4*)x;
    const float4* w1v = (const float4*)w1;

    for (int kc = 0; kc < 128; kc += 64) {
#pragma unroll
        for (int i = 0; i < 4; ++i) {
            int v = tid + i * 256;
            int row = v >> 4, c4 = v & 15;
            float4 val = xv[(size_t)(m0 + row) * 32 + (kc >> 2) + c4];
            *(float4*)&As[row * 72 + c4 * 4] = val;
        }
#pragma unroll
        for (int i = 0; i < 8; ++i) {
            int v = tid + i * 256;
            int k = v >> 5, c4 = v & 31;
            float4 val = w1v[(size_t)(kc + k) * 32 + c4];
            *(float4*)&Ws[k * 132 + c4 * 4] = val;
        }
        __syncthreads();

        const float* a0p = &As[(ty * 4 + 0) * 72];
        const float* a1p = &As[(ty * 4 + 1) * 72];
        const float* a2p = &As[(ty * 4 + 2) * 72];
        const float* a3p = &As[(ty * 4 + 3) * 72];
#pragma unroll 4
        for (int k = 0; k < 64; ++k) {
            float4 bA = *(const float4*)&Ws[k * 132 + tx * 8];
            float4 bB = *(const float4*)&Ws[k * 132 + tx * 8 + 4];
            float a0 = a0p[k], a1 = a1p[k], a2 = a2p[k], a3 = a3p[k];
            acc[0][0] += a0 * bA.x; acc[0][1] += a0 * bA.y; acc[0][2] += a0 * bA.z; acc[0][3] += a0 * bA.w;
            acc[0][4] += a0 * bB.x; acc[0][5] += a0 * bB.y; acc[0][6] += a0 * bB.z; acc[0][7] += a0 * bB.w;
            acc[1][0] += a1 * bA.x; acc[1][1] += a1 * bA.y; acc[1][2] += a1 * bA.z; acc[1][3] += a1 * bA.w;
            acc[1][4] += a1 * bB.x; acc[1][5] += a1 * bB.y; acc[1][6] += a1 * bB.z; acc[1][7] += a1 * bB.w;
            acc[2][0] += a2 * bA.x; acc[2][1] += a2 * bA.y; acc[2][2] += a2 * bA.z; acc[2][3] += a2 * bA.w;
            acc[2][4] += a2 * bB.x; acc[2][5] += a2 * bB.y; acc[2][6] += a2 * bB.z; acc[2][7] += a2 * bB.w;
            acc[3][0] += a3 * bA.x; acc[3][1] += a3 * bA.y; acc[3][2] += a3 * bA.z; acc[3][3] += a3 * bA.w;
            acc[3][4] += a3 * bB.x; acc[3][5] += a3 * bB.y; acc[3][6] += a3 * bB.z; acc[3][7] += a3 * bB.w;
        }
        __syncthreads();
    }

    float4 g1a = ((const float4*)g1)[tx * 2], g1b = ((const float4*)g1)[tx * 2 + 1];
    float4 b1a = ((const float4*)b1)[tx * 2], b1b = ((const float4*)b1)[tx * 2 + 1];
    float* Hs = Ws;
#pragma unroll
    for (int i = 0; i < 4; ++i) {
        int row = ty * 4 + i;
        float4 hA, hB;
        hA.x = fmaxf(acc[i][0] * g1a.x + b1a.x, 0.f);
        hA.y = fmaxf(acc[i][1] * g1a.y + b1a.y, 0.f);
        hA.z = fmaxf(acc[i][2] * g1a.z + b1a.z, 0.f);
        hA.w = fmaxf(acc[i][3] * g1a.w + b1a.w, 0.f);
        hB.x = fmaxf(acc[i][4] * g1b.x + b1b.x, 0.f);
        hB.y = fmaxf(acc[i][5] * g1b.y + b1b.y, 0.f);
        hB.z = fmaxf(acc[i][6] * g1b.z + b1b.z, 0.f);
        hB.w = fmaxf(acc[i][7] * g1b.w + b1b.w, 0.f);
        *(float4*)&Hs[row * 132 + tx * 8] = hA;
        *(float4*)&Hs[row * 132 + tx * 8 + 4] = hB;
    }
    __syncthreads();

    const int r = tid >> 2;
    const int p = tid & 3;
    float a2[10];
#pragma unroll
    for (int c = 0; c < 10; ++c) a2[c] = 0.f;
    for (int kk = 0; kk < 32; ++kk) {
        int k = kk * 4 + p;
        float hv = Hs[r * 132 + k];
#pragma unroll
        for (int c = 0; c < 10; ++c) a2[c] += hv * W2s[k * 10 + c];
    }
#pragma unroll
    for (int c = 0; c < 10; ++c) {
        a2[c] += __shfl_xor(a2[c], 1);
        a2[c] += __shfl_xor(a2[c], 2);
    }
    if (p == 0) {
        int m = m0 + r;
        float best = -INFINITY;
        int bi = 0;
#pragma unroll
        for (int c = 0; c < 10; ++c) {
            float s = a2[c] + b2[c];
            out_s10[(size_t)m * 10 + c] = s;
            if (s > best) { best = s; bi = c; }
        }
        out_heat[m] = best;
        cls[m] = bi;
        int b = m / NF;
        unsigned i = (unsigned)(m - b * NF);
        float sig = 1.0f / (1.0f + expf(-best));
        unsigned of = ordf(sig);
        keys[m] = ((unsigned long long)of << 32) | (unsigned)(~i);
        atomicAdd(&hist[((size_t)b << 14) + (of >> 18)], 1u);
    }
}

// ---------------------------------------------------------------------------
// K2: blocks 0-15 = topk collect (8 per batch): read prebuilt global hist,
// redundantly compute identical threshold, collect candidates from own
// 2500-key slice into global candbuf; last-arriving block per batch ranks
// and emits (deadlock-free last-block pattern, device-scope atomics+fences).
// Blocks 16-47 = grid SCAN+SCATTER (unchanged).
// ---------------------------------------------------------------------------
#define H1BINS 16384

__global__ __launch_bounds__(1024) void mid_kernel(
    const unsigned long long* __restrict__ keys,
    const int* __restrict__ cls,
    const int* __restrict__ fcoords,
    float* __restrict__ out1,
    float* __restrict__ out4,
    int* __restrict__ tki,
    float* __restrict__ keyworld,
    const int* __restrict__ sca, const int* __restrict__ scb,
    const int* __restrict__ bh,
    int* __restrict__ gstart,
    float2* __restrict__ pts, int* __restrict__ pidx,
    const unsigned* __restrict__ hist,
    unsigned* __restrict__ ccount,
    unsigned* __restrict__ done,
    unsigned long long* __restrict__ candbuf)
{
    __shared__ unsigned h[H1BINS];            // 64 KB
    __shared__ unsigned sA[1024], sB[1024];   // 8 KB scan buffers
    __shared__ unsigned long long list[1024]; // 8 KB
    __shared__ unsigned chunk_s, aboveC_s, T1_s, aboveT1_s, cand_s, thr_s, cnt_s;
    __shared__ unsigned lastflag;
    const int tid = threadIdx.x;
    const int blk = blockIdx.x;

    if (blk >= 2 * TKB) {
        // ---- grid scan + scatter for slice (sb, j) ----
        const int idx = blk - 2 * TKB;      // 0..31
        const int sb = idx >> 3;            // 0..3
        const int j = idx & (GB - 1);       // 0..7
        const int s = sb >> 1, b = sb & 1;
        const int n = s ? CELLS_B : CELLS_A;
        const int nc = s ? NCB : NCA;
        const float stride = s ? 8.0f : 4.0f;
        const float inv_h = s ? (1.0f / HB) : (1.0f / HA);
        const int stb = STB(s, b);
        const int2* sc = ((const int2*)(s ? scb : sca)) + (size_t)b * NS;
        const int4* scv = (const int4*)sc;
        const size_t pbase = ((size_t)s * BB + b) * NS;
        const int* bhsb = bh + (sb << 14);  // sb * GB * 2048
        int* tot = (int*)h;                 // [0..2047]
        int* cur = ((int*)h) + 2048;        // pre, then cursor  [2048..4095]
        int* scn0 = (int*)sA;
        int* scn1 = (int*)sB;

        for (int c = tid; c < 2048; c += 1024) {
            int t = 0, pr = 0;
#pragma unroll
            for (int g = 0; g < GB; ++g) {
                int v = bhsb[(g << 11) + c];
                t += v;
                if (g < j) pr += v;
            }
            tot[c] = t;
            cur[c] = pr;                    // pre-sum for this block's cursor
        }
        __syncthreads();
        // exclusive scan over tot[0..n-1]; thread owns cells 2t, 2t+1
        const int i0 = tid * 2, i1 = tid * 2 + 1;
        int c0 = (i0 < n) ? tot[i0] : 0;
        int c1 = (i1 < n) ? tot[i1] : 0;
        scn0[tid] = c0 + c1;
        __syncthreads();
        int* srcp = scn0; int* dstp = scn1;
        for (int off = 1; off < 1024; off <<= 1) {
            int v = srcp[tid];
            if (tid >= off) v += srcp[tid - off];
            dstp[tid] = v;
            __syncthreads();
            int* t = srcp; srcp = dstp; dstp = t;
        }
        const int excl = (tid == 0) ? 0 : srcp[tid - 1];
        if (i0 < n) {
            if (j == 0) gstart[stb + i0] = excl;
            cur[i0] += excl;
        }
        if (i1 < n) {
            if (j == 0) gstart[stb + i1] = excl + c0;
            cur[i1] += excl + c0;
        }
        if (j == 0 && tid == 0) gstart[stb + n] = NS;
        __syncthreads();
        // scatter this block's slice
        for (int p = j * SLICE4 + tid; p < (j + 1) * SLICE4; p += 1024) {
            int4 v = scv[p];
            float sx0, sy0, sx1, sy1;
            int cell0 = cell_of(v.x, v.y, stride, inv_h, nc, sx0, sy0);
            int cell1 = cell_of(v.z, v.w, stride, inv_h, nc, sx1, sy1);
            int pos0 = atomicAdd(&cur[cell0], 1);
            int pos1 = atomicAdd(&cur[cell1], 1);
            pts[pbase + pos0] = make_float2(sx0, sy0);
            pidx[pbase + pos0] = p * 2;
            pts[pbase + pos1] = make_float2(sx1, sy1);
            pidx[pbase + pos1] = p * 2 + 1;
        }
        return;
    }

    // ---- topk collect for (batch b, slice j) ----
    const int b = blk >> 3;                 // TKB == 8
    const int j = blk & (TKB - 1);
    const unsigned long long* kb = keys + (size_t)b * NF;
    const unsigned K = NK;

    // load prebuilt histogram
    for (int i = tid; i < H1BINS; i += 1024) h[i] = hist[((size_t)b << 14) + i];
    __syncthreads();
    unsigned ck = 0;
    {
        int base = tid * 16;
#pragma unroll
        for (int jj = 0; jj < 16; ++jj) ck += h[base + jj];
        sA[tid] = ck;
    }
    __syncthreads();
    // inclusive suffix scan over 1024 chunk sums
    unsigned* srcp = sA; unsigned* dstp = sB;
    for (int off = 1; off < 1024; off <<= 1) {
        unsigned v = srcp[tid];
        if (tid + off < 1024) v += srcp[tid + off];
        dstp[tid] = v;
        __syncthreads();
        unsigned* t = srcp; srcp = dstp; dstp = t;
    }
    {
        unsigned suf = srcp[tid];
        unsigned above = suf - ck;
        if (above < K && K <= suf) { chunk_s = (unsigned)tid; aboveC_s = above; }
    }
    __syncthreads();
    if (tid == 0) {
        int bin = (int)chunk_s * 16 + 15;
        unsigned acc = aboveC_s;
        for (;; --bin) { if (acc + h[bin] >= K) break; acc += h[bin]; }
        T1_s = (unsigned)bin;
        aboveT1_s = acc;
        cand_s = acc + h[bin];
        cnt_s = 0u;
    }
    __syncthreads();
    const unsigned T1 = T1_s;
    const unsigned cand = cand_s;

    if (cand <= 1024u) {
        // collect my slice into the global candidate buffer
        for (int i = j * TSLICE + tid; i < (j + 1) * TSLICE; i += 1024) {
            unsigned long long key = kb[i];
            if ((unsigned)(key >> 50) >= T1) {
                unsigned pos = atomicAdd(&ccount[b], 1u);
                candbuf[(b << 10) + pos] = key;
            }
        }
    }
    __syncthreads();
    __threadfence();
    if (tid == 0) {
        unsigned old = atomicAdd(&done[b], 1u);
        lastflag = (old == (unsigned)(TKB - 1)) ? 1u : 0u;
    }
    __syncthreads();
    if (!lastflag) return;
    __threadfence();   // acquire: make other blocks' candbuf stores visible

    int cc;
    if (cand <= 1024u) {
        cc = (int)cand;
        for (int i = tid; i < cc; i += 1024) list[i] = candbuf[(b << 10) + i];
        __syncthreads();
    } else {
        // rare fallback: refine to 24-bit threshold over full NF, single block
        const unsigned K2 = K - aboveT1_s;
        h[tid] = 0u;
        __syncthreads();
#pragma unroll 4
        for (int i = tid; i < NF; i += 1024) {
            unsigned long long key = kb[i];
            if ((unsigned)(key >> 50) == T1)
                atomicAdd(&h[(unsigned)(key >> 40) & 1023u], 1u);
        }
        __syncthreads();
        unsigned hb = h[tid];
        sA[tid] = hb;
        __syncthreads();
        unsigned* s2 = sA; unsigned* d2 = sB;
        for (int off = 1; off < 1024; off <<= 1) {
            unsigned v = s2[tid];
            if (tid + off < 1024) v += s2[tid + off];
            d2[tid] = v;
            __syncthreads();
            unsigned* t = s2; s2 = d2; d2 = t;
        }
        {
            unsigned suf = s2[tid];
            unsigned above = suf - hb;
            if (above < K2 && K2 <= suf) thr_s = (T1 << 10) | (unsigned)tid;
        }
        __syncthreads();
        const unsigned thr24 = thr_s;
#pragma unroll 4
        for (int i = tid; i < NF; i += 1024) {
            unsigned long long key = kb[i];
            if ((unsigned)(key >> 40) >= thr24) {
                unsigned pos = atomicAdd(&cnt_s, 1u);
                if (pos < 1024u) list[pos] = key;
            }
        }
        __syncthreads();
        cc = (int)(cnt_s > 1024u ? 1024u : cnt_s);
    }

    // exhaustive ranking: keys unique -> exact permutation, no barriers
    if (tid < cc) {
        unsigned long long mykey = list[tid];
        unsigned r = 0;
#pragma unroll 8
        for (int jj = 0; jj < cc; ++jj) r += (list[jj] > mykey) ? 1u : 0u;
        if (r < (unsigned)NK) {
            int idx = (int)(~(unsigned)(mykey & 0xFFFFFFFFull));
            tki[b * NK + (int)r] = idx;
            int c0 = fcoords[((size_t)b * NF + idx) * 2 + 0];
            int c1 = fcoords[((size_t)b * NF + idx) * 2 + 1];
            size_t o = (size_t)(b * NK + (int)r);
            out1[o * 3 + 0] = (float)b;
            out1[o * 3 + 1] = (float)c0;
            out1[o * 3 + 2] = (float)c1;
            float wx = __fadd_rn(__fmul_rn(__fmul_rn(__fadd_rn((float)c0, 0.5f), 8.0f), 0.075f), -54.0f);
            float wy = __fadd_rn(__fmul_rn(__fmul_rn(__fadd_rn((float)c1, 0.5f), 8.0f), 0.075f), -54.0f);
            keyworld[o * 2 + 0] = wx;
            keyworld[o * 2 + 1] = wy;
            out4[o] = (float)cls[(size_t)b * NF + idx];
        }
    }
}

// ---------------------------------------------------------------------------
// K3: grid-accelerated radius-KNN (unchanged).
// ---------------------------------------------------------------------------
__global__ __launch_bounds__(256) void knn_kernel(
    const float* __restrict__ sfa, const float* __restrict__ sfb,
    const int* __restrict__ gstart,
    const float2* __restrict__ pts, const int* __restrict__ pidx,
    const float* __restrict__ knn_w,
    const float* __restrict__ knn_b,
    const float* __restrict__ keyworld,
    float* __restrict__ mf)
{
    __shared__ unsigned long long list[1024];
    __shared__ float psum[128];
    __shared__ unsigned cnt_s;
    const int tid = threadIdx.x;
    const int blk = blockIdx.x;
    const int s = blk / (BB * NK);
    const int rest = blk % (BB * NK);
    const int b = rest / NK;
    const int r = rest % NK;
    const float* sfeat = s ? sfb : sfa;
    const float r2 = s ? (float)(4.8 * 4.8) : (float)(2.4 * 2.4);
    const float inv_h = s ? (1.0f / HB) : (1.0f / HA);
    const int nc = s ? NCB : NCA;
    const int stb = STB(s, b);
    const size_t pbase = ((size_t)s * BB + b) * NS;

    if (tid == 0) cnt_s = 0u;
    __syncthreads();
    const float kx = keyworld[((size_t)b * NK + r) * 2 + 0];
    const float ky = keyworld[((size_t)b * NK + r) * 2 + 1];
    int cx = (int)floorf((kx + 54.0f) * inv_h);
    int cy = (int)floorf((ky + 54.0f) * inv_h);
    cx = min(max(cx, 0), nc - 1);
    cy = min(max(cy, 0), nc - 1);
    const int c0 = max(cx - 1, 0), c1 = min(cx + 1, nc - 1);
    const int cy0 = max(cy - 1, 0), cy1 = min(cy + 1, nc - 1);

    for (int cyy = cy0; cyy <= cy1; ++cyy) {
        int lo = gstart[stb + cyy * nc + c0];
        int hi = gstart[stb + cyy * nc + c1 + 1];
        for (int p = lo + tid; p < hi; p += 256) {
            float2 w = pts[pbase + p];
            float dx = __fsub_rn(kx, w.x);
            float dy = __fsub_rn(ky, w.y);
            float d2 = __fadd_rn(__fmul_rn(dx, dx), __fmul_rn(dy, dy));
            if (d2 <= r2) {
                unsigned pos = atomicAdd(&cnt_s, 1u);
                if (pos < 1024u)
                    list[pos] = ((unsigned long long)__float_as_uint(d2) << 32)
                              | (unsigned)pidx[pbase + p];
            }
        }
    }
    __syncthreads();
    int cc = (int)cnt_s;
    if (cc > 1024) cc = 1024;
    int n2 = 16;
    while (n2 < cc) n2 <<= 1;
    for (int i = tid; i < n2; i += 256)
        if (i >= cc) list[i] = ~0ull;
    __syncthreads();
    for (int kk = 2; kk <= n2; kk <<= 1) {
        for (int j = kk >> 1; j > 0; j >>= 1) {
            for (int i = tid; i < n2; i += 256) {
                int ixj = i ^ j;
                if (ixj > i) {
                    unsigned long long a = list[i], bv = list[ixj];
                    bool up = ((i & kk) == 0);
                    bool sw = up ? (a > bv) : (a < bv);
                    if (sw) { list[i] = bv; list[ixj] = a; }
                }
            }
            __syncthreads();
        }
    }
    {
        int K = cc < KNN ? cc : KNN;
        int col = tid & 127, half = tid >> 7;
        float acc = 0.f;
        int k0 = half * 8, k1 = min(K, half * 8 + 8);
        for (int k = k0; k < k1; ++k) {
            unsigned i = (unsigned)(list[k] & 0xFFFFFFFFull);
            acc += knn_w[s * 16 + k] * sfeat[((size_t)b * NS + i) * CH + col];
        }
        if (half) psum[col] = acc;
        __syncthreads();
        if (!half)
            mf[(((size_t)s * BB + b) * NK + r) * CH + col] = knn_b[s] + acc + psum[col];
    }
}

// ---------------------------------------------------------------------------
// K4: fuse MLP (unchanged: direct L2-resident float4 weight loads,
// 8-16 in flight, transposed activations, split-K tree reduce).
// ---------------------------------------------------------------------------
__global__ __launch_bounds__(1024) void fuse_kernel(
    const float* __restrict__ ffeat,
    const int* __restrict__ tki,
    const float* __restrict__ kw_w1, const float* __restrict__ kw_g1,
    const float* __restrict__ kw_b1, const float* __restrict__ kw_w2,
    const float* __restrict__ kw_b2,
    const float* __restrict__ fuse_w1, const float* __restrict__ fuse_g1,
    const float* __restrict__ fuse_b1, const float* __restrict__ fuse_w2,
    const float* __restrict__ fuse_b2,
    const float* __restrict__ mf,
    float* __restrict__ out0)
{
    __shared__ float pL[16384];     // 64 KB split-K partials
    __shared__ float xsT[512];      // x transposed [k][key]
    __shared__ float mfs[1024];     // [src][key][c]
    __shared__ float fusedvT[1024]; // [k][key]
    __shared__ float h2sT[1024];    // [k][key]
    __shared__ float prm[964];      // kw_g1|kw_b1|kw_w2|kw_b2|fg1|fb1|fb2
    __shared__ float hsX[256];      // kw hidden [key][k]
    __shared__ float p2[96];
    __shared__ float l3[12];
    __shared__ float wsm[8];
    __shared__ int idxs[KPB], bs[KPB], rs[KPB];
    const int tid = threadIdx.x;
    const int f0 = blockIdx.x * KPB;

    if (tid < 964) {
        float v;
        if (tid < 64)       v = kw_g1[tid];
        else if (tid < 128) v = kw_b1[tid - 64];
        else if (tid < 320) v = kw_w2[tid - 128];
        else if (tid < 323) v = kw_b2[tid - 320];
        else if (tid < 324) v = 0.f;
        else if (tid < 580) v = fuse_g1[tid - 324];
        else if (tid < 836) v = fuse_b1[tid - 580];
        else                v = fuse_b2[tid - 836];
        prm[tid] = v;
    }
    if (tid < KPB) {
        int flat = f0 + tid;
        int b = flat / NK;
        bs[tid] = b;
        rs[tid] = flat - b * NK;
        idxs[tid] = tki[flat];
    }
    __syncthreads();

    if (tid < 128) {
        int key = tid >> 5, c4 = tid & 31;
        float4 v = ((const float4*)(ffeat + ((size_t)bs[key] * NF + idxs[key]) * CH))[c4];
        xsT[(c4 * 4 + 0) * 4 + key] = v.x;
        xsT[(c4 * 4 + 1) * 4 + key] = v.y;
        xsT[(c4 * 4 + 2) * 4 + key] = v.z;
        xsT[(c4 * 4 + 3) * 4 + key] = v.w;
    }
    if (tid < 256) {
        int ss = tid >> 7, key = (tid >> 5) & 3, c4 = tid & 31;
        float4 v = ((const float4*)(mf + (((size_t)ss * BB + bs[key]) * NK + rs[key]) * CH))[c4];
        *(float4*)&mfs[ss * 512 + key * 128 + c4 * 4] = v;
    }
    __syncthreads();

    if (tid < 256) {
        const int og = tid & 15, kseg = tid >> 4;
        float4 wr[8];
#pragma unroll
        for (int m = 0; m < 8; ++m)
            wr[m] = ((const float4*)kw_w1)[(kseg * 8 + m) * 16 + og];
        float4 a0 = {0, 0, 0, 0}, a1 = {0, 0, 0, 0}, a2 = {0, 0, 0, 0}, a3 = {0, 0, 0, 0};
#pragma unroll
        for (int m = 0; m < 8; ++m) {
            float4 f4 = *(const float4*)&xsT[(kseg * 8 + m) * 4];
            fma4(a0, f4.x, wr[m]);
            fma4(a1, f4.y, wr[m]);
            fma4(a2, f4.z, wr[m]);
            fma4(a3, f4.w, wr[m]);
        }
        *(float4*)&pL[(kseg * 4 + 0) * 64 + og * 4] = a0;
        *(float4*)&pL[(kseg * 4 + 1) * 64 + og * 4] = a1;
        *(float4*)&pL[(kseg * 4 + 2) * 64 + og * 4] = a2;
        *(float4*)&pL[(kseg * 4 + 3) * 64 + og * 4] = a3;
    }
    __syncthreads();
    if (tid < 256) {
        int out = tid >> 2, key = tid & 3;
        float s = 0.f;
#pragma unroll
        for (int ks = 0; ks < 16; ++ks) s += pL[(ks * 4 + key) * 64 + out];
        float t = s * prm[out] + prm[64 + out];
        hsX[key * 64 + out] = t > 0.f ? t : 0.f;
    }
    __syncthreads();
    if (tid < 96) {
        int key = tid / 24, rr = tid % 24, out = rr >> 3, seg = rr & 7;
        float acc = 0.f;
#pragma unroll
        for (int m = 0; m < 8; ++m) {
            int k = seg * 8 + m;
            acc += hsX[key * 64 + k] * prm[128 + k * 3 + out];
        }
        p2[(key * 3 + out) * 8 + seg] = acc;
    }
    __syncthreads();
    if (tid < 12) {
        int key = tid / 3, out = tid % 3;
        float s = 0.f;
#pragma unroll
        for (int j = 0; j < 8; ++j) s += p2[(key * 3 + out) * 8 + j];
        l3[key * 3 + out] = s + prm[320 + out];
    }
    __syncthreads();
    if (tid < KPB) {
        float l0 = l3[tid * 3], l1 = l3[tid * 3 + 1], l2 = l3[tid * 3 + 2];
        float m = fmaxf(l0, fmaxf(l1, l2));
        float e0 = expf(l0 - m), e1 = expf(l1 - m), e2 = expf(l2 - m);
        float sum = e0 + e1 + e2;
        wsm[tid * 2 + 0] = e0 / sum;
        wsm[tid * 2 + 1] = e1 / sum;
    }
    __syncthreads();

    {
        int c = tid >> 2, key = tid & 3;
        float w0 = wsm[key * 2], w1_ = wsm[key * 2 + 1];
        float val;
        if (c < 128) {
            float xv_ = xsT[c * 4 + key];
            float m0 = mfs[key * 128 + c];
            float m1 = mfs[512 + key * 128 + c];
            float kv = w0 * xv_;
            float kv2 = w1_ * kv;
            val = kv * m0 + kv2 * m1;
        } else {
            float xv_ = xsT[(c - 128) * 4 + key];
            val = w1_ * (w0 * xv_);
        }
        fusedvT[tid] = val;
    }
    __syncthreads();

    {
        const int og = tid & 63, kseg = tid >> 6;
        const float4* w1v = (const float4*)fuse_w1;
        float4 wr[16];
#pragma unroll
        for (int m = 0; m < 16; ++m)
            wr[m] = w1v[(kseg * 16 + m) * 64 + og];
        float4 a0 = {0, 0, 0, 0}, a1 = {0, 0, 0, 0}, a2 = {0, 0, 0, 0}, a3 = {0, 0, 0, 0};
#pragma unroll
        for (int m = 0; m < 16; ++m) {
            float4 f4 = *(const float4*)&fusedvT[(kseg * 16 + m) * 4];
            fma4(a0, f4.x, wr[m]);
            fma4(a1, f4.y, wr[m]);
            fma4(a2, f4.z, wr[m]);
            fma4(a3, f4.w, wr[m]);
        }
        *(float4*)&pL[(kseg * 4 + 0) * 256 + og * 4] = a0;
        *(float4*)&pL[(kseg * 4 + 1) * 256 + og * 4] = a1;
        *(float4*)&pL[(kseg * 4 + 2) * 256 + og * 4] = a2;
        *(float4*)&pL[(kseg * 4 + 3) * 256 + og * 4] = a3;
    }
    __syncthreads();
    {
        int out = tid >> 2, key = tid & 3;
        float s = 0.f;
#pragma unroll
        for (int ks = 0; ks < 16; ++ks) s += pL[(ks * 4 + key) * 256 + out];
        float t = s * prm[324 + out] + prm[580 + out];
        h2sT[out * 4 + key] = t > 0.f ? t : 0.f;
    }
    __syncthreads();

    {
        const int og2 = tid & 31, kseg2 = tid >> 5;
        const float4* w2v = (const float4*)fuse_w2;
        float4 wr[8];
#pragma unroll
        for (int m = 0; m < 8; ++m)
            wr[m] = w2v[(kseg2 * 8 + m) * 32 + og2];
        float4 a0 = {0, 0, 0, 0}, a1 = {0, 0, 0, 0}, a2 = {0, 0, 0, 0}, a3 = {0, 0, 0, 0};
#pragma unroll
        for (int m = 0; m < 8; ++m) {
            float4 f4 = *(const float4*)&h2sT[(kseg2 * 8 + m) * 4];
            fma4(a0, f4.x, wr[m]);
            fma4(a1, f4.y, wr[m]);
            fma4(a2, f4.z, wr[m]);
            fma4(a3, f4.w, wr[m]);
        }
        *(float4*)&pL[(kseg2 * 4 + 0) * 128 + og2 * 4] = a0;
        *(float4*)&pL[(kseg2 * 4 + 1) * 128 + og2 * 4] = a1;
        *(float4*)&pL[(kseg2 * 4 + 2) * 128 + og2 * 4] = a2;
        *(float4*)&pL[(kseg2 * 4 + 3) * 128 + og2 * 4] = a3;
    }
    __syncthreads();
    if (tid < 512) {
        int out = tid >> 2, key = tid & 3;
        float s = prm[836 + out];
#pragma unroll
        for (int ks = 0; ks < 32; ++ks) s += pL[(ks * 4 + key) * 128 + out];
        out0[((size_t)bs[key] * NK + rs[key]) * CH + out] = s;
    }
}

extern "C" void kernel_launch(void* const* d_in, const int* in_sizes, int n_in,
                              void* d_out, int out_size, void* d_ws, size_t ws_size,
                              hipStream_t stream)
{
    const float* fusion_feat = (const float*)d_in[0];
    const float* src_feat_a  = (const float*)d_in[1];
    const float* src_feat_b  = (const float*)d_in[2];
    const float* heat_w1 = (const float*)d_in[3];
    const float* heat_g1 = (const float*)d_in[4];
    const float* heat_b1 = (const float*)d_in[5];
    const float* heat_w2 = (const float*)d_in[6];
    const float* heat_b2 = (const float*)d_in[7];
    const float* knn_w   = (const float*)d_in[8];
    const float* knn_b   = (const float*)d_in[9];
    const float* kw_w1   = (const float*)d_in[10];
    const float* kw_g1   = (const float*)d_in[11];
    const float* kw_b1   = (const float*)d_in[12];
    const float* kw_w2   = (const float*)d_in[13];
    const float* kw_b2   = (const float*)d_in[14];
    const float* fuse_w1 = (const float*)d_in[15];
    const float* fuse_g1 = (const float*)d_in[16];
    const float* fuse_b1 = (const float*)d_in[17];
    const float* fuse_w2 = (const float*)d_in[18];
    const float* fuse_b2 = (const float*)d_in[19];
    const int* fusion_coords = (const int*)d_in[20];
    const int* src_coords_a  = (const int*)d_in[21];
    const int* src_coords_b  = (const int*)d_in[22];

    float* out = (float*)d_out;
    char* ws = (char*)d_ws;
    int* cls = (int*)(ws + WS_CLS);
    int* tki = (int*)(ws + WS_TKI);
    float* keyworld = (float*)(ws + WS_KW);
    float* mf = (float*)(ws + WS_MF);
    unsigned long long* keys = (unsigned long long*)(ws + WS_KEYS);
    int* bh = (int*)(ws + WS_BH);
    unsigned* hist = (unsigned*)(ws + WS_HIST);
    unsigned* done = (unsigned*)(ws + WS_DONE);
    unsigned* ccount = (unsigned*)(ws + WS_CCNT);
    unsigned long long* candbuf = (unsigned long long*)(ws + WS_CAND);
    int* gstart = (int*)(ws + WS_GSTART);
    float2* pts = (float2*)(ws + WS_PTS);
    int* pidx = (int*)(ws + WS_PIDX);

    // zero hist (128 KB) + done (8 B) + ccount (8 B): contiguous region
    hipMemsetAsync(ws + WS_HIST, 0, 131072 + 16, stream);

    heat_kernel<<<(BB * NF) / 64 + 4 * GB, 256, 0, stream>>>(
        fusion_feat, heat_w1, heat_g1, heat_b1, heat_w2, heat_b2,
        out + OUT2_OFF, out + OUT3_OFF, cls, keys,
        src_coords_a, src_coords_b, bh, hist);

    mid_kernel<<<2 * TKB + 4 * GB, 1024, 0, stream>>>(
        keys, cls, fusion_coords,
        out + OUT1_OFF, out + OUT4_OFF, tki, keyworld,
        src_coords_a, src_coords_b, bh, gstart, pts, pidx,
        hist, ccount, done, candbuf);

    knn_kernel<<<2 * BB * NK, 256, 0, stream>>>(
        src_feat_a, src_feat_b, gstart, pts, pidx,
        knn_w, knn_b, keyworld, mf);

    fuse_kernel<<<(BB * NK) / KPB, 1024, 0, stream>>>(
        fusion_feat, tki, kw_w1, kw_g1, kw_b1, kw_w2, kw_b2,
        fuse_w1, fuse_g1, fuse_b1, fuse_w2, fuse_b2, mf, out + OUT0_OFF);
}

// Round 4
// 250.100 us; speedup vs baseline: 1.3118x; 1.3118x over previous
//
#include <hip/hip_runtime.h>
#include <math.h>

#define BB 2
#define NF 20000
#define NS 30000
#define CH 128
#define NK 500
#define KNN 16
#define KPB 4

// grid params: cell = 1.001 * radius (margin vs float boundary rounding)
#define HA 2.4024f
#define HB 4.8048f
#define NCA 45
#define NCB 23
#define CELLS_A 2025
#define CELLS_B 529

// multi-block counting sort for the spatial grid
#define GB 8                 // count/scatter blocks per (s,b)
#define SLICE 3750           // NS / GB points per block
#define SLICE4 1875          // int4 (2-point) loads per slice

// output offsets (floats, concatenated in return order)
#define OUT0_OFF 0           // out          (B*NK*128) = 128000
#define OUT1_OFF 128000      // key_voxel_indices (B*NK*3) = 3000
#define OUT2_OFF 131000      // heat_scores  (B*NF) = 40000
#define OUT3_OFF 171000      // scores10     (B*NF*10) = 400000
#define OUT4_OFF 571000      // key_class    (B*NK) = 1000

// workspace offsets (bytes)
#define WS_CLS   0           // int32  x 40000
#define WS_TKI   160000      // int32  x 1000
#define WS_KW    164000      // float  x 2000
#define WS_MF    172000      // float  x 256000 (1,024,000 B)
#define WS_KEYS  WS_MF       // u64 x 40000 overlays mf head (temporally disjoint)
#define WS_BH    492000      // int x 65536: per-block hists [sb][g][2048], overlays mf tail
#define WS_GSTART 1196000    // int x 5112 (cell starts, +1 per (s,b))
#define WS_PTS    1236880    // float2 x 120000 (sorted world coords)
#define WS_PIDX   2196880    // int x 120000 (sorted original indices)

#define STB(s,b)  ((s) ? (4052 + (b) * 530) : ((b) * 2026))

__device__ __forceinline__ void fma4(float4& acc, float sc, const float4& wv) {
    acc.x += sc * wv.x; acc.y += sc * wv.y;
    acc.z += sc * wv.z; acc.w += sc * wv.w;
}

__device__ __forceinline__ unsigned ordf(float s) {
    unsigned u = __float_as_uint(s);
    return (u & 0x80000000u) ? ~u : (u | 0x80000000u);
}

// identical arithmetic in count and scatter phases (bitwise-consistent cells)
__device__ __forceinline__ int cell_of(int cxi, int cyi, float stride, float inv_h,
                                       int nc, float& sx, float& sy)
{
    sx = __fadd_rn(__fmul_rn(__fmul_rn(__fadd_rn((float)cxi, 0.5f), stride), 0.075f), -54.0f);
    sy = __fadd_rn(__fmul_rn(__fmul_rn(__fadd_rn((float)cyi, 0.5f), stride), 0.075f), -54.0f);
    int cx = (int)floorf((sx + 54.0f) * inv_h);
    int cy = (int)floorf((sy + 54.0f) * inv_h);
    cx = min(max(cx, 0), nc - 1);
    cy = min(max(cy, 0), nc - 1);
    return cy * nc + cx;
}

// ---------------------------------------------------------------------------
// K1: blocks 0-31 = grid COUNT phase (8 blocks per (s,b), private per-block
// histograms); blocks 32+ = heat MLP SGEMM. (R3's global topk-hist atomics
// reverted: clustered-bin global atomics cost +90us of XCD cacheline
// ping-pong. Histogramming stays in mid, now wave-aggregated in LDS.)
// ---------------------------------------------------------------------------
__global__ __launch_bounds__(256) void heat_kernel(
    const float* __restrict__ x,
    const float* __restrict__ w1,
    const float* __restrict__ g1, const float* __restrict__ b1,
    const float* __restrict__ w2,
    const float* __restrict__ b2,
    float* __restrict__ out_heat,
    float* __restrict__ out_s10,
    int* __restrict__ cls,
    unsigned long long* __restrict__ keys,
    const int* __restrict__ sca, const int* __restrict__ scb,
    int* __restrict__ bh)
{
    __shared__ float As[64 * 72];
    __shared__ float Ws[64 * 132];
    __shared__ float W2s[1280];
    const int tid = threadIdx.x;

    if (blockIdx.x < 4 * GB) {
        const int gflat = blockIdx.x;
        const int sb = gflat >> 3;          // 0..3
        const int gg = gflat & (GB - 1);    // 0..7
        const int s = sb >> 1, b = sb & 1;
        const float stride = s ? 8.0f : 4.0f;
        const float inv_h = s ? (1.0f / HB) : (1.0f / HA);
        const int nc = s ? NCB : NCA;
        const int2* sc = ((const int2*)(s ? scb : sca)) + (size_t)b * NS;
        const int4* scv = (const int4*)sc;
        int* hist_l = (int*)As;             // 2048 ints

        for (int i = tid; i < 2048; i += 256) hist_l[i] = 0;
        __syncthreads();
        for (int p = gg * SLICE4 + tid; p < (gg + 1) * SLICE4; p += 256) {
            int4 v = scv[p];
            float sx, sy;
            int cell0 = cell_of(v.x, v.y, stride, inv_h, nc, sx, sy);
            int cell1 = cell_of(v.z, v.w, stride, inv_h, nc, sx, sy);
            atomicAdd(&hist_l[cell0], 1);
            atomicAdd(&hist_l[cell1], 1);
        }
        __syncthreads();
        int* bhp = bh + (gflat << 11);
        for (int i = tid; i < 2048; i += 256) bhp[i] = hist_l[i];
        return;
    }

    const int m0 = (blockIdx.x - 4 * GB) * 64;
    const int tx = tid & 15;
    const int ty = tid >> 4;

    for (int v = tid; v < 1280; v += 256) W2s[v] = w2[v];

    float acc[4][8];
#pragma unroll
    for (int i = 0; i < 4; ++i)
#pragma unroll
        for (int j = 0; j < 8; ++j) acc[i][j] = 0.f;

    const float4* xv = (const float4*)x;
    const float4* w1v = (const float4*)w1;

    for (int kc = 0; kc < 128; kc += 64) {
#pragma unroll
        for (int i = 0; i < 4; ++i) {
            int v = tid + i * 256;
            int row = v >> 4, c4 = v & 15;
            float4 val = xv[(size_t)(m0 + row) * 32 + (kc >> 2) + c4];
            *(float4*)&As[row * 72 + c4 * 4] = val;
        }
#pragma unroll
        for (int i = 0; i < 8; ++i) {
            int v = tid + i * 256;
            int k = v >> 5, c4 = v & 31;
            float4 val = w1v[(size_t)(kc + k) * 32 + c4];
            *(float4*)&Ws[k * 132 + c4 * 4] = val;
        }
        __syncthreads();

        const float* a0p = &As[(ty * 4 + 0) * 72];
        const float* a1p = &As[(ty * 4 + 1) * 72];
        const float* a2p = &As[(ty * 4 + 2) * 72];
        const float* a3p = &As[(ty * 4 + 3) * 72];
#pragma unroll 4
        for (int k = 0; k < 64; ++k) {
            float4 bA = *(const float4*)&Ws[k * 132 + tx * 8];
            float4 bB = *(const float4*)&Ws[k * 132 + tx * 8 + 4];
            float a0 = a0p[k], a1 = a1p[k], a2 = a2p[k], a3 = a3p[k];
            acc[0][0] += a0 * bA.x; acc[0][1] += a0 * bA.y; acc[0][2] += a0 * bA.z; acc[0][3] += a0 * bA.w;
            acc[0][4] += a0 * bB.x; acc[0][5] += a0 * bB.y; acc[0][6] += a0 * bB.z; acc[0][7] += a0 * bB.w;
            acc[1][0] += a1 * bA.x; acc[1][1] += a1 * bA.y; acc[1][2] += a1 * bA.z; acc[1][3] += a1 * bA.w;
            acc[1][4] += a1 * bB.x; acc[1][5] += a1 * bB.y; acc[1][6] += a1 * bB.z; acc[1][7] += a1 * bB.w;
            acc[2][0] += a2 * bA.x; acc[2][1] += a2 * bA.y; acc[2][2] += a2 * bA.z; acc[2][3] += a2 * bA.w;
            acc[2][4] += a2 * bB.x; acc[2][5] += a2 * bB.y; acc[2][6] += a2 * bB.z; acc[2][7] += a2 * bB.w;
            acc[3][0] += a3 * bA.x; acc[3][1] += a3 * bA.y; acc[3][2] += a3 * bA.z; acc[3][3] += a3 * bA.w;
            acc[3][4] += a3 * bB.x; acc[3][5] += a3 * bB.y; acc[3][6] += a3 * bB.z; acc[3][7] += a3 * bB.w;
        }
        __syncthreads();
    }

    float4 g1a = ((const float4*)g1)[tx * 2], g1b = ((const float4*)g1)[tx * 2 + 1];
    float4 b1a = ((const float4*)b1)[tx * 2], b1b = ((const float4*)b1)[tx * 2 + 1];
    float* Hs = Ws;
#pragma unroll
    for (int i = 0; i < 4; ++i) {
        int row = ty * 4 + i;
        float4 hA, hB;
        hA.x = fmaxf(acc[i][0] * g1a.x + b1a.x, 0.f);
        hA.y = fmaxf(acc[i][1] * g1a.y + b1a.y, 0.f);
        hA.z = fmaxf(acc[i][2] * g1a.z + b1a.z, 0.f);
        hA.w = fmaxf(acc[i][3] * g1a.w + b1a.w, 0.f);
        hB.x = fmaxf(acc[i][4] * g1b.x + b1b.x, 0.f);
        hB.y = fmaxf(acc[i][5] * g1b.y + b1b.y, 0.f);
        hB.z = fmaxf(acc[i][6] * g1b.z + b1b.z, 0.f);
        hB.w = fmaxf(acc[i][7] * g1b.w + b1b.w, 0.f);
        *(float4*)&Hs[row * 132 + tx * 8] = hA;
        *(float4*)&Hs[row * 132 + tx * 8 + 4] = hB;
    }
    __syncthreads();

    const int r = tid >> 2;
    const int p = tid & 3;
    float a2[10];
#pragma unroll
    for (int c = 0; c < 10; ++c) a2[c] = 0.f;
    for (int kk = 0; kk < 32; ++kk) {
        int k = kk * 4 + p;
        float hv = Hs[r * 132 + k];
#pragma unroll
        for (int c = 0; c < 10; ++c) a2[c] += hv * W2s[k * 10 + c];
    }
#pragma unroll
    for (int c = 0; c < 10; ++c) {
        a2[c] += __shfl_xor(a2[c], 1);
        a2[c] += __shfl_xor(a2[c], 2);
    }
    if (p == 0) {
        int m = m0 + r;
        float best = -INFINITY;
        int bi = 0;
#pragma unroll
        for (int c = 0; c < 10; ++c) {
            float s = a2[c] + b2[c];
            out_s10[(size_t)m * 10 + c] = s;
            if (s > best) { best = s; bi = c; }
        }
        out_heat[m] = best;
        cls[m] = bi;
        int b = m / NF;
        unsigned i = (unsigned)(m - b * NF);
        float sig = 1.0f / (1.0f + expf(-best));
        keys[m] = ((unsigned long long)ordf(sig) << 32) | (unsigned)(~i);
    }
}

// ---------------------------------------------------------------------------
// K2: blocks 0-1 = topk (wave-aggregated LDS histogram: ballot-match equal
// bins -> one atomic per distinct bin per wave; bin ids cached in LDS u16 so
// the collect pass scans LDS and gathers only candidate keys from global,
// with ballot-compacted position allocation). Blocks 2-33 = grid
// SCAN+SCATTER (unchanged).
// ---------------------------------------------------------------------------
#define H1BINS 16384

__global__ __launch_bounds__(1024) void mid_kernel(
    const unsigned long long* __restrict__ keys,
    const int* __restrict__ cls,
    const int* __restrict__ fcoords,
    float* __restrict__ out1,
    float* __restrict__ out4,
    int* __restrict__ tki,
    float* __restrict__ keyworld,
    const int* __restrict__ sca, const int* __restrict__ scb,
    const int* __restrict__ bh,
    int* __restrict__ gstart,
    float2* __restrict__ pts, int* __restrict__ pidx)
{
    __shared__ unsigned h[H1BINS];            // 64 KB
    __shared__ unsigned sA[1024], sB[1024];   // 8 KB scan buffers
    __shared__ unsigned long long list[1024]; // 8 KB
    __shared__ unsigned short bins16[NF];     // 40 KB cached bin ids
    __shared__ unsigned chunk_s, aboveC_s, T1_s, aboveT1_s, cand_s, thr_s, cnt_s;
    const int tid = threadIdx.x;
    const int blk = blockIdx.x;

    if (blk >= 2) {
        // ---- grid scan + scatter for slice (sb, j) ----
        const int idx = blk - 2;            // 0..31
        const int sb = idx >> 3;            // 0..3
        const int j = idx & (GB - 1);       // 0..7
        const int s = sb >> 1, b = sb & 1;
        const int n = s ? CELLS_B : CELLS_A;
        const int nc = s ? NCB : NCA;
        const float stride = s ? 8.0f : 4.0f;
        const float inv_h = s ? (1.0f / HB) : (1.0f / HA);
        const int stb = STB(s, b);
        const int2* sc = ((const int2*)(s ? scb : sca)) + (size_t)b * NS;
        const int4* scv = (const int4*)sc;
        const size_t pbase = ((size_t)s * BB + b) * NS;
        const int* bhsb = bh + (sb << 14);  // sb * GB * 2048
        int* tot = (int*)h;                 // [0..2047]
        int* cur = ((int*)h) + 2048;        // pre, then cursor  [2048..4095]
        int* scn0 = (int*)sA;
        int* scn1 = (int*)sB;

        for (int c = tid; c < 2048; c += 1024) {
            int t = 0, pr = 0;
#pragma unroll
            for (int g = 0; g < GB; ++g) {
                int v = bhsb[(g << 11) + c];
                t += v;
                if (g < j) pr += v;
            }
            tot[c] = t;
            cur[c] = pr;                    // pre-sum for this block's cursor
        }
        __syncthreads();
        // exclusive scan over tot[0..n-1]; thread owns cells 2t, 2t+1
        const int i0 = tid * 2, i1 = tid * 2 + 1;
        int c0 = (i0 < n) ? tot[i0] : 0;
        int c1 = (i1 < n) ? tot[i1] : 0;
        scn0[tid] = c0 + c1;
        __syncthreads();
        int* srcp = scn0; int* dstp = scn1;
        for (int off = 1; off < 1024; off <<= 1) {
            int v = srcp[tid];
            if (tid >= off) v += srcp[tid - off];
            dstp[tid] = v;
            __syncthreads();
            int* t = srcp; srcp = dstp; dstp = t;
        }
        const int excl = (tid == 0) ? 0 : srcp[tid - 1];
        if (i0 < n) {
            if (j == 0) gstart[stb + i0] = excl;
            cur[i0] += excl;
        }
        if (i1 < n) {
            if (j == 0) gstart[stb + i1] = excl + c0;
            cur[i1] += excl + c0;
        }
        if (j == 0 && tid == 0) gstart[stb + n] = NS;
        __syncthreads();
        // scatter this block's slice
        for (int p = j * SLICE4 + tid; p < (j + 1) * SLICE4; p += 1024) {
            int4 v = scv[p];
            float sx0, sy0, sx1, sy1;
            int cell0 = cell_of(v.x, v.y, stride, inv_h, nc, sx0, sy0);
            int cell1 = cell_of(v.z, v.w, stride, inv_h, nc, sx1, sy1);
            int pos0 = atomicAdd(&cur[cell0], 1);
            int pos1 = atomicAdd(&cur[cell1], 1);
            pts[pbase + pos0] = make_float2(sx0, sy0);
            pidx[pbase + pos0] = p * 2;
            pts[pbase + pos1] = make_float2(sx1, sy1);
            pidx[pbase + pos1] = p * 2 + 1;
        }
        return;
    }

    // ---- topk for batch b = blk ----
    const int b = blk;
    const unsigned long long* kb = keys + (size_t)b * NF;
    const unsigned K = NK;
    const int lane = tid & 63;

    for (int i = tid; i < H1BINS; i += 1024) h[i] = 0u;
    __syncthreads();
    // wave-aggregated histogram: one LDS atomic per distinct bin per wave
    for (int i = tid; i < NF; i += 1024) {
        unsigned long long key = kb[i];
        unsigned bin = (unsigned)(key >> 50);
        bins16[i] = (unsigned short)bin;
        unsigned long long todo = __ballot(1);
        while (todo) {
            int leader = (int)__ffsll((unsigned long long)todo) - 1;
            unsigned lbin = (unsigned)__shfl((int)bin, leader);
            unsigned long long same = __ballot(bin == lbin);
            if (lane == leader) atomicAdd(&h[lbin], (unsigned)__popcll(same));
            todo &= ~same;
        }
    }
    __syncthreads();
    unsigned ck = 0;
    {
        int base = tid * 16;
#pragma unroll
        for (int j = 0; j < 16; ++j) ck += h[base + j];
        sA[tid] = ck;
    }
    __syncthreads();
    // inclusive suffix scan over 1024 chunk sums
    unsigned* srcp = sA; unsigned* dstp = sB;
    for (int off = 1; off < 1024; off <<= 1) {
        unsigned v = srcp[tid];
        if (tid + off < 1024) v += srcp[tid + off];
        dstp[tid] = v;
        __syncthreads();
        unsigned* t = srcp; srcp = dstp; dstp = t;
    }
    {
        unsigned suf = srcp[tid];
        unsigned above = suf - ck;
        if (above < K && K <= suf) { chunk_s = (unsigned)tid; aboveC_s = above; }
    }
    __syncthreads();
    if (tid == 0) {
        int bin = (int)chunk_s * 16 + 15;
        unsigned acc = aboveC_s;
        for (;; --bin) { if (acc + h[bin] >= K) break; acc += h[bin]; }
        T1_s = (unsigned)bin;
        aboveT1_s = acc;
        cand_s = acc + h[bin];
        cnt_s = 0u;
    }
    __syncthreads();
    const unsigned T1 = T1_s;

    if (cand_s <= 1024u) {
        // collect via cached LDS bins: gather only candidate keys from global;
        // ballot-compacted position allocation (one atomic per wave-iter)
        for (int i = tid; i < NF; i += 1024) {
            bool pred = ((unsigned)bins16[i] >= T1);
            unsigned long long m = __ballot(pred);
            if (m) {
                int leader = (int)__ffsll((unsigned long long)m) - 1;
                unsigned base = 0;
                if (lane == leader) base = atomicAdd(&cnt_s, (unsigned)__popcll(m));
                base = (unsigned)__shfl((int)base, leader);
                if (pred) {
                    unsigned pos = base + (unsigned)__popcll(m & ((1ull << lane) - 1ull));
                    if (pos < 1024u) list[pos] = kb[i];
                }
            }
        }
    } else {
        // fallback: refine to 24-bit threshold (rare: >1024 keys in one bin)
        const unsigned K2 = K - aboveT1_s;
        h[tid] = 0u;
        __syncthreads();
#pragma unroll 4
        for (int i = tid; i < NF; i += 1024) {
            unsigned long long key = kb[i];
            if ((unsigned)(key >> 50) == T1)
                atomicAdd(&h[(unsigned)(key >> 40) & 1023u], 1u);
        }
        __syncthreads();
        unsigned hb = h[tid];
        sA[tid] = hb;
        __syncthreads();
        unsigned* s2 = sA; unsigned* d2 = sB;
        for (int off = 1; off < 1024; off <<= 1) {
            unsigned v = s2[tid];
            if (tid + off < 1024) v += s2[tid + off];
            d2[tid] = v;
            __syncthreads();
            unsigned* t = s2; s2 = d2; d2 = t;
        }
        {
            unsigned suf = s2[tid];
            unsigned above = suf - hb;
            if (above < K2 && K2 <= suf) thr_s = (T1 << 10) | (unsigned)tid;
        }
        __syncthreads();
        const unsigned thr24 = thr_s;
#pragma unroll 4
        for (int i = tid; i < NF; i += 1024) {
            unsigned long long key = kb[i];
            if ((unsigned)(key >> 40) >= thr24) {
                unsigned pos = atomicAdd(&cnt_s, 1u);
                if (pos < 1024u) list[pos] = key;
            }
        }
    }
    __syncthreads();
    const int cc = (int)(cnt_s > 1024u ? 1024u : cnt_s);

    // exhaustive ranking: keys unique -> exact permutation, no barriers
    if (tid < cc) {
        unsigned long long mykey = list[tid];
        unsigned r = 0;
#pragma unroll 8
        for (int j = 0; j < cc; ++j) r += (list[j] > mykey) ? 1u : 0u;
        if (r < (unsigned)NK) {
            int idx = (int)(~(unsigned)(mykey & 0xFFFFFFFFull));
            tki[b * NK + (int)r] = idx;
            int c0 = fcoords[((size_t)b * NF + idx) * 2 + 0];
            int c1 = fcoords[((size_t)b * NF + idx) * 2 + 1];
            size_t o = (size_t)(b * NK + (int)r);
            out1[o * 3 + 0] = (float)b;
            out1[o * 3 + 1] = (float)c0;
            out1[o * 3 + 2] = (float)c1;
            float wx = __fadd_rn(__fmul_rn(__fmul_rn(__fadd_rn((float)c0, 0.5f), 8.0f), 0.075f), -54.0f);
            float wy = __fadd_rn(__fmul_rn(__fmul_rn(__fadd_rn((float)c1, 0.5f), 8.0f), 0.075f), -54.0f);
            keyworld[o * 2 + 0] = wx;
            keyworld[o * 2 + 1] = wy;
            out4[o] = (float)cls[(size_t)b * NF + idx];
        }
    }
}

// ---------------------------------------------------------------------------
// K3: grid-accelerated radius-KNN (unchanged).
// ---------------------------------------------------------------------------
__global__ __launch_bounds__(256) void knn_kernel(
    const float* __restrict__ sfa, const float* __restrict__ sfb,
    const int* __restrict__ gstart,
    const float2* __restrict__ pts, const int* __restrict__ pidx,
    const float* __restrict__ knn_w,
    const float* __restrict__ knn_b,
    const float* __restrict__ keyworld,
    float* __restrict__ mf)
{
    __shared__ unsigned long long list[1024];
    __shared__ float psum[128];
    __shared__ unsigned cnt_s;
    const int tid = threadIdx.x;
    const int blk = blockIdx.x;
    const int s = blk / (BB * NK);
    const int rest = blk % (BB * NK);
    const int b = rest / NK;
    const int r = rest % NK;
    const float* sfeat = s ? sfb : sfa;
    const float r2 = s ? (float)(4.8 * 4.8) : (float)(2.4 * 2.4);
    const float inv_h = s ? (1.0f / HB) : (1.0f / HA);
    const int nc = s ? NCB : NCA;
    const int stb = STB(s, b);
    const size_t pbase = ((size_t)s * BB + b) * NS;

    if (tid == 0) cnt_s = 0u;
    __syncthreads();
    const float kx = keyworld[((size_t)b * NK + r) * 2 + 0];
    const float ky = keyworld[((size_t)b * NK + r) * 2 + 1];
    int cx = (int)floorf((kx + 54.0f) * inv_h);
    int cy = (int)floorf((ky + 54.0f) * inv_h);
    cx = min(max(cx, 0), nc - 1);
    cy = min(max(cy, 0), nc - 1);
    const int c0 = max(cx - 1, 0), c1 = min(cx + 1, nc - 1);
    const int cy0 = max(cy - 1, 0), cy1 = min(cy + 1, nc - 1);

    for (int cyy = cy0; cyy <= cy1; ++cyy) {
        int lo = gstart[stb + cyy * nc + c0];
        int hi = gstart[stb + cyy * nc + c1 + 1];
        for (int p = lo + tid; p < hi; p += 256) {
            float2 w = pts[pbase + p];
            float dx = __fsub_rn(kx, w.x);
            float dy = __fsub_rn(ky, w.y);
            float d2 = __fadd_rn(__fmul_rn(dx, dx), __fmul_rn(dy, dy));
            if (d2 <= r2) {
                unsigned pos = atomicAdd(&cnt_s, 1u);
                if (pos < 1024u)
                    list[pos] = ((unsigned long long)__float_as_uint(d2) << 32)
                              | (unsigned)pidx[pbase + p];
            }
        }
    }
    __syncthreads();
    int cc = (int)cnt_s;
    if (cc > 1024) cc = 1024;
    int n2 = 16;
    while (n2 < cc) n2 <<= 1;
    for (int i = tid; i < n2; i += 256)
        if (i >= cc) list[i] = ~0ull;
    __syncthreads();
    for (int kk = 2; kk <= n2; kk <<= 1) {
        for (int j = kk >> 1; j > 0; j >>= 1) {
            for (int i = tid; i < n2; i += 256) {
                int ixj = i ^ j;
                if (ixj > i) {
                    unsigned long long a = list[i], bv = list[ixj];
                    bool up = ((i & kk) == 0);
                    bool sw = up ? (a > bv) : (a < bv);
                    if (sw) { list[i] = bv; list[ixj] = a; }
                }
            }
            __syncthreads();
        }
    }
    {
        int K = cc < KNN ? cc : KNN;
        int col = tid & 127, half = tid >> 7;
        float acc = 0.f;
        int k0 = half * 8, k1 = min(K, half * 8 + 8);
        for (int k = k0; k < k1; ++k) {
            unsigned i = (unsigned)(list[k] & 0xFFFFFFFFull);
            acc += knn_w[s * 16 + k] * sfeat[((size_t)b * NS + i) * CH + col];
        }
        if (half) psum[col] = acc;
        __syncthreads();
        if (!half)
            mf[(((size_t)s * BB + b) * NK + r) * CH + col] = knn_b[s] + acc + psum[col];
    }
}

// ---------------------------------------------------------------------------
// K4: fuse MLP (unchanged: direct L2-resident float4 weight loads,
// 8-16 in flight, transposed activations, split-K tree reduce).
// ---------------------------------------------------------------------------
__global__ __launch_bounds__(1024) void fuse_kernel(
    const float* __restrict__ ffeat,
    const int* __restrict__ tki,
    const float* __restrict__ kw_w1, const float* __restrict__ kw_g1,
    const float* __restrict__ kw_b1, const float* __restrict__ kw_w2,
    const float* __restrict__ kw_b2,
    const float* __restrict__ fuse_w1, const float* __restrict__ fuse_g1,
    const float* __restrict__ fuse_b1, const float* __restrict__ fuse_w2,
    const float* __restrict__ fuse_b2,
    const float* __restrict__ mf,
    float* __restrict__ out0)
{
    __shared__ float pL[16384];     // 64 KB split-K partials
    __shared__ float xsT[512];      // x transposed [k][key]
    __shared__ float mfs[1024];     // [src][key][c]
    __shared__ float fusedvT[1024]; // [k][key]
    __shared__ float h2sT[1024];    // [k][key]
    __shared__ float prm[964];      // kw_g1|kw_b1|kw_w2|kw_b2|fg1|fb1|fb2
    __shared__ float hsX[256];      // kw hidden [key][k]
    __shared__ float p2[96];
    __shared__ float l3[12];
    __shared__ float wsm[8];
    __shared__ int idxs[KPB], bs[KPB], rs[KPB];
    const int tid = threadIdx.x;
    const int f0 = blockIdx.x * KPB;

    if (tid < 964) {
        float v;
        if (tid < 64)       v = kw_g1[tid];
        else if (tid < 128) v = kw_b1[tid - 64];
        else if (tid < 320) v = kw_w2[tid - 128];
        else if (tid < 323) v = kw_b2[tid - 320];
        else if (tid < 324) v = 0.f;
        else if (tid < 580) v = fuse_g1[tid - 324];
        else if (tid < 836) v = fuse_b1[tid - 580];
        else                v = fuse_b2[tid - 836];
        prm[tid] = v;
    }
    if (tid < KPB) {
        int flat = f0 + tid;
        int b = flat / NK;
        bs[tid] = b;
        rs[tid] = flat - b * NK;
        idxs[tid] = tki[flat];
    }
    __syncthreads();

    if (tid < 128) {
        int key = tid >> 5, c4 = tid & 31;
        float4 v = ((const float4*)(ffeat + ((size_t)bs[key] * NF + idxs[key]) * CH))[c4];
        xsT[(c4 * 4 + 0) * 4 + key] = v.x;
        xsT[(c4 * 4 + 1) * 4 + key] = v.y;
        xsT[(c4 * 4 + 2) * 4 + key] = v.z;
        xsT[(c4 * 4 + 3) * 4 + key] = v.w;
    }
    if (tid < 256) {
        int ss = tid >> 7, key = (tid >> 5) & 3, c4 = tid & 31;
        float4 v = ((const float4*)(mf + (((size_t)ss * BB + bs[key]) * NK + rs[key]) * CH))[c4];
        *(float4*)&mfs[ss * 512 + key * 128 + c4 * 4] = v;
    }
    __syncthreads();

    if (tid < 256) {
        const int og = tid & 15, kseg = tid >> 4;
        float4 wr[8];
#pragma unroll
        for (int m = 0; m < 8; ++m)
            wr[m] = ((const float4*)kw_w1)[(kseg * 8 + m) * 16 + og];
        float4 a0 = {0, 0, 0, 0}, a1 = {0, 0, 0, 0}, a2 = {0, 0, 0, 0}, a3 = {0, 0, 0, 0};
#pragma unroll
        for (int m = 0; m < 8; ++m) {
            float4 f4 = *(const float4*)&xsT[(kseg * 8 + m) * 4];
            fma4(a0, f4.x, wr[m]);
            fma4(a1, f4.y, wr[m]);
            fma4(a2, f4.z, wr[m]);
            fma4(a3, f4.w, wr[m]);
        }
        *(float4*)&pL[(kseg * 4 + 0) * 64 + og * 4] = a0;
        *(float4*)&pL[(kseg * 4 + 1) * 64 + og * 4] = a1;
        *(float4*)&pL[(kseg * 4 + 2) * 64 + og * 4] = a2;
        *(float4*)&pL[(kseg * 4 + 3) * 64 + og * 4] = a3;
    }
    __syncthreads();
    if (tid < 256) {
        int out = tid >> 2, key = tid & 3;
        float s = 0.f;
#pragma unroll
        for (int ks = 0; ks < 16; ++ks) s += pL[(ks * 4 + key) * 64 + out];
        float t = s * prm[out] + prm[64 + out];
        hsX[key * 64 + out] = t > 0.f ? t : 0.f;
    }
    __syncthreads();
    if (tid < 96) {
        int key = tid / 24, rr = tid % 24, out = rr >> 3, seg = rr & 7;
        float acc = 0.f;
#pragma unroll
        for (int m = 0; m < 8; ++m) {
            int k = seg * 8 + m;
            acc += hsX[key * 64 + k] * prm[128 + k * 3 + out];
        }
        p2[(key * 3 + out) * 8 + seg] = acc;
    }
    __syncthreads();
    if (tid < 12) {
        int key = tid / 3, out = tid % 3;
        float s = 0.f;
#pragma unroll
        for (int j = 0; j < 8; ++j) s += p2[(key * 3 + out) * 8 + j];
        l3[key * 3 + out] = s + prm[320 + out];
    }
    __syncthreads();
    if (tid < KPB) {
        float l0 = l3[tid * 3], l1 = l3[tid * 3 + 1], l2 = l3[tid * 3 + 2];
        float m = fmaxf(l0, fmaxf(l1, l2));
        float e0 = expf(l0 - m), e1 = expf(l1 - m), e2 = expf(l2 - m);
        float sum = e0 + e1 + e2;
        wsm[tid * 2 + 0] = e0 / sum;
        wsm[tid * 2 + 1] = e1 / sum;
    }
    __syncthreads();

    {
        int c = tid >> 2, key = tid & 3;
        float w0 = wsm[key * 2], w1_ = wsm[key * 2 + 1];
        float val;
        if (c < 128) {
            float xv_ = xsT[c * 4 + key];
            float m0 = mfs[key * 128 + c];
            float m1 = mfs[512 + key * 128 + c];
            float kv = w0 * xv_;
            float kv2 = w1_ * kv;
            val = kv * m0 + kv2 * m1;
        } else {
            float xv_ = xsT[(c - 128) * 4 + key];
            val = w1_ * (w0 * xv_);
        }
        fusedvT[tid] = val;
    }
    __syncthreads();

    {
        const int og = tid & 63, kseg = tid >> 6;
        const float4* w1v = (const float4*)fuse_w1;
        float4 wr[16];
#pragma unroll
        for (int m = 0; m < 16; ++m)
            wr[m] = w1v[(kseg * 16 + m) * 64 + og];
        float4 a0 = {0, 0, 0, 0}, a1 = {0, 0, 0, 0}, a2 = {0, 0, 0, 0}, a3 = {0, 0, 0, 0};
#pragma unroll
        for (int m = 0; m < 16; ++m) {
            float4 f4 = *(const float4*)&fusedvT[(kseg * 16 + m) * 4];
            fma4(a0, f4.x, wr[m]);
            fma4(a1, f4.y, wr[m]);
            fma4(a2, f4.z, wr[m]);
            fma4(a3, f4.w, wr[m]);
        }
        *(float4*)&pL[(kseg * 4 + 0) * 256 + og * 4] = a0;
        *(float4*)&pL[(kseg * 4 + 1) * 256 + og * 4] = a1;
        *(float4*)&pL[(kseg * 4 + 2) * 256 + og * 4] = a2;
        *(float4*)&pL[(kseg * 4 + 3) * 256 + og * 4] = a3;
    }
    __syncthreads();
    {
        int out = tid >> 2, key = tid & 3;
        float s = 0.f;
#pragma unroll
        for (int ks = 0; ks < 16; ++ks) s += pL[(ks * 4 + key) * 256 + out];
        float t = s * prm[324 + out] + prm[580 + out];
        h2sT[out * 4 + key] = t > 0.f ? t : 0.f;
    }
    __syncthreads();

    {
        const int og2 = tid & 31, kseg2 = tid >> 5;
        const float4* w2v = (const float4*)fuse_w2;
        float4 wr[8];
#pragma unroll
        for (int m = 0; m < 8; ++m)
            wr[m] = w2v[(kseg2 * 8 + m) * 32 + og2];
        float4 a0 = {0, 0, 0, 0}, a1 = {0, 0, 0, 0}, a2 = {0, 0, 0, 0}, a3 = {0, 0, 0, 0};
#pragma unroll
        for (int m = 0; m < 8; ++m) {
            float4 f4 = *(const float4*)&h2sT[(kseg2 * 8 + m) * 4];
            fma4(a0, f4.x, wr[m]);
            fma4(a1, f4.y, wr[m]);
            fma4(a2, f4.z, wr[m]);
            fma4(a3, f4.w, wr[m]);
        }
        *(float4*)&pL[(kseg2 * 4 + 0) * 128 + og2 * 4] = a0;
        *(float4*)&pL[(kseg2 * 4 + 1) * 128 + og2 * 4] = a1;
        *(float4*)&pL[(kseg2 * 4 + 2) * 128 + og2 * 4] = a2;
        *(float4*)&pL[(kseg2 * 4 + 3) * 128 + og2 * 4] = a3;
    }
    __syncthreads();
    if (tid < 512) {
        int out = tid >> 2, key = tid & 3;
        float s = prm[836 + out];
#pragma unroll
        for (int ks = 0; ks < 32; ++ks) s += pL[(ks * 4 + key) * 128 + out];
        out0[((size_t)bs[key] * NK + rs[key]) * CH + out] = s;
    }
}

extern "C" void kernel_launch(void* const* d_in, const int* in_sizes, int n_in,
                              void* d_out, int out_size, void* d_ws, size_t ws_size,
                              hipStream_t stream)
{
    const float* fusion_feat = (const float*)d_in[0];
    const float* src_feat_a  = (const float*)d_in[1];
    const float* src_feat_b  = (const float*)d_in[2];
    const float* heat_w1 = (const float*)d_in[3];
    const float* heat_g1 = (const float*)d_in[4];
    const float* heat_b1 = (const float*)d_in[5];
    const float* heat_w2 = (const float*)d_in[6];
    const float* heat_b2 = (const float*)d_in[7];
    const float* knn_w   = (const float*)d_in[8];
    const float* knn_b   = (const float*)d_in[9];
    const float* kw_w1   = (const float*)d_in[10];
    const float* kw_g1   = (const float*)d_in[11];
    const float* kw_b1   = (const float*)d_in[12];
    const float* kw_w2   = (const float*)d_in[13];
    const float* kw_b2   = (const float*)d_in[14];
    const float* fuse_w1 = (const float*)d_in[15];
    const float* fuse_g1 = (const float*)d_in[16];
    const float* fuse_b1 = (const float*)d_in[17];
    const float* fuse_w2 = (const float*)d_in[18];
    const float* fuse_b2 = (const float*)d_in[19];
    const int* fusion_coords = (const int*)d_in[20];
    const int* src_coords_a  = (const int*)d_in[21];
    const int* src_coords_b  = (const int*)d_in[22];

    float* out = (float*)d_out;
    char* ws = (char*)d_ws;
    int* cls = (int*)(ws + WS_CLS);
    int* tki = (int*)(ws + WS_TKI);
    float* keyworld = (float*)(ws + WS_KW);
    float* mf = (float*)(ws + WS_MF);
    unsigned long long* keys = (unsigned long long*)(ws + WS_KEYS);
    int* bh = (int*)(ws + WS_BH);
    int* gstart = (int*)(ws + WS_GSTART);
    float2* pts = (float2*)(ws + WS_PTS);
    int* pidx = (int*)(ws + WS_PIDX);

    heat_kernel<<<(BB * NF) / 64 + 4 * GB, 256, 0, stream>>>(
        fusion_feat, heat_w1, heat_g1, heat_b1, heat_w2, heat_b2,
        out + OUT2_OFF, out + OUT3_OFF, cls, keys,
        src_coords_a, src_coords_b, bh);

    mid_kernel<<<2 + 4 * GB, 1024, 0, stream>>>(
        keys, cls, fusion_coords,
        out + OUT1_OFF, out + OUT4_OFF, tki, keyworld,
        src_coords_a, src_coords_b, bh, gstart, pts, pidx);

    knn_kernel<<<2 * BB * NK, 256, 0, stream>>>(
        src_feat_a, src_feat_b, gstart, pts, pidx,
        knn_w, knn_b, keyworld, mf);

    fuse_kernel<<<(BB * NK) / KPB, 1024, 0, stream>>>(
        fusion_feat, tki, kw_w1, kw_g1, kw_b1, kw_w2, kw_b2,
        fuse_w1, fuse_g1, fuse_b1, fuse_w2, fuse_b2, mf, out + OUT0_OFF);
}

// Round 5
// 232.289 us; speedup vs baseline: 1.4124x; 1.0767x over previous
//
#include <hip/hip_runtime.h>
#include <math.h>

#define BB 2
#define NF 20000
#define NS 30000
#define CH 128
#define NK 500
#define KNN 16
#define KPB 4

// grid params: cell = 1.001 * radius (margin vs float boundary rounding)
#define HA 2.4024f
#define HB 4.8048f
#define NCA 45
#define NCB 23
#define CELLS_A 2025
#define CELLS_B 529

// multi-block counting sort for the spatial grid
#define GB 8                 // count/scatter blocks per (s,b)
#define SLICE 3750           // NS / GB points per block
#define SLICE4 1875          // int4 (2-point) loads per slice

// output offsets (floats, concatenated in return order)
#define OUT0_OFF 0           // out          (B*NK*128) = 128000
#define OUT1_OFF 128000      // key_voxel_indices (B*NK*3) = 3000
#define OUT2_OFF 131000      // heat_scores  (B*NF) = 40000
#define OUT3_OFF 171000      // scores10     (B*NF*10) = 400000
#define OUT4_OFF 571000      // key_class    (B*NK) = 1000

// workspace offsets (bytes)
#define WS_CLS   0           // int32  x 40000
#define WS_TKI   160000      // int32  x 1000
#define WS_KW    164000      // float  x 2000
#define WS_MF    172000      // float  x 256000 (1,024,000 B)
#define WS_KEYS  WS_MF       // u64 x 40000 overlays mf head (temporally disjoint)
#define WS_BH    492000      // int x 65536: per-block hists [sb][g][2048], overlays mf tail
#define WS_GSTART 1196000    // int x 5112 (cell starts, +1 per (s,b))
#define WS_PTS    1236880    // float2 x 120000 (sorted world coords)
#define WS_PIDX   2196880    // int x 120000 (sorted original indices)

#define STB(s,b)  ((s) ? (4052 + (b) * 530) : ((b) * 2026))

__device__ __forceinline__ void fma4(float4& acc, float sc, const float4& wv) {
    acc.x += sc * wv.x; acc.y += sc * wv.y;
    acc.z += sc * wv.z; acc.w += sc * wv.w;
}

__device__ __forceinline__ unsigned ordf(float s) {
    unsigned u = __float_as_uint(s);
    return (u & 0x80000000u) ? ~u : (u | 0x80000000u);
}

// identical arithmetic in count and scatter phases (bitwise-consistent cells)
__device__ __forceinline__ int cell_of(int cxi, int cyi, float stride, float inv_h,
                                       int nc, float& sx, float& sy)
{
    sx = __fadd_rn(__fmul_rn(__fmul_rn(__fadd_rn((float)cxi, 0.5f), stride), 0.075f), -54.0f);
    sy = __fadd_rn(__fmul_rn(__fmul_rn(__fadd_rn((float)cyi, 0.5f), stride), 0.075f), -54.0f);
    int cx = (int)floorf((sx + 54.0f) * inv_h);
    int cy = (int)floorf((sy + 54.0f) * inv_h);
    cx = min(max(cx, 0), nc - 1);
    cy = min(max(cy, 0), nc - 1);
    return cy * nc + cx;
}

// ---------------------------------------------------------------------------
// K1: blocks 0-31 = grid COUNT phase (8 blocks per (s,b), private per-block
// histograms); blocks 32+ = heat MLP SGEMM.
// Bank-conflict fixes this round: As row stride 72->76 (A-col reads were
// 4-way on bank 0 across ty groups; now 2-way = free), and the B-fragment
// read split into two 4-word-stride float4 reads (tx*4 and 64+tx*4; the old
// tx*8 stride was a 4-way conflict on every ds_read_b128 cycle).
// ---------------------------------------------------------------------------
__global__ __launch_bounds__(256) void heat_kernel(
    const float* __restrict__ x,
    const float* __restrict__ w1,
    const float* __restrict__ g1, const float* __restrict__ b1,
    const float* __restrict__ w2,
    const float* __restrict__ b2,
    float* __restrict__ out_heat,
    float* __restrict__ out_s10,
    int* __restrict__ cls,
    unsigned long long* __restrict__ keys,
    const int* __restrict__ sca, const int* __restrict__ scb,
    int* __restrict__ bh)
{
    __shared__ float As[64 * 76];   // padded stride (was 72)
    __shared__ float Ws[64 * 132];
    __shared__ float W2s[1280];
    const int tid = threadIdx.x;

    if (blockIdx.x < 4 * GB) {
        const int gflat = blockIdx.x;
        const int sb = gflat >> 3;          // 0..3
        const int gg = gflat & (GB - 1);    // 0..7
        const int s = sb >> 1, b = sb & 1;
        const float stride = s ? 8.0f : 4.0f;
        const float inv_h = s ? (1.0f / HB) : (1.0f / HA);
        const int nc = s ? NCB : NCA;
        const int2* sc = ((const int2*)(s ? scb : sca)) + (size_t)b * NS;
        const int4* scv = (const int4*)sc;
        int* hist_l = (int*)As;             // 2048 ints

        for (int i = tid; i < 2048; i += 256) hist_l[i] = 0;
        __syncthreads();
        for (int p = gg * SLICE4 + tid; p < (gg + 1) * SLICE4; p += 256) {
            int4 v = scv[p];
            float sx, sy;
            int cell0 = cell_of(v.x, v.y, stride, inv_h, nc, sx, sy);
            int cell1 = cell_of(v.z, v.w, stride, inv_h, nc, sx, sy);
            atomicAdd(&hist_l[cell0], 1);
            atomicAdd(&hist_l[cell1], 1);
        }
        __syncthreads();
        int* bhp = bh + (gflat << 11);
        for (int i = tid; i < 2048; i += 256) bhp[i] = hist_l[i];
        return;
    }

    const int m0 = (blockIdx.x - 4 * GB) * 64;
    const int tx = tid & 15;
    const int ty = tid >> 4;

    for (int v = tid; v < 1280; v += 256) W2s[v] = w2[v];

    float acc[4][8];
#pragma unroll
    for (int i = 0; i < 4; ++i)
#pragma unroll
        for (int j = 0; j < 8; ++j) acc[i][j] = 0.f;

    const float4* xv = (const float4*)x;
    const float4* w1v = (const float4*)w1;

    for (int kc = 0; kc < 128; kc += 64) {
#pragma unroll
        for (int i = 0; i < 4; ++i) {
            int v = tid + i * 256;
            int row = v >> 4, c4 = v & 15;
            float4 val = xv[(size_t)(m0 + row) * 32 + (kc >> 2) + c4];
            *(float4*)&As[row * 76 + c4 * 4] = val;
        }
#pragma unroll
        for (int i = 0; i < 8; ++i) {
            int v = tid + i * 256;
            int k = v >> 5, c4 = v & 31;
            float4 val = w1v[(size_t)(kc + k) * 32 + c4];
            *(float4*)&Ws[k * 132 + c4 * 4] = val;
        }
        __syncthreads();

        const float* a0p = &As[(ty * 4 + 0) * 76];
        const float* a1p = &As[(ty * 4 + 1) * 76];
        const float* a2p = &As[(ty * 4 + 2) * 76];
        const float* a3p = &As[(ty * 4 + 3) * 76];
#pragma unroll 4
        for (int k = 0; k < 64; ++k) {
            // acc[.][0..3] = hidden cols tx*4..tx*4+3 ; acc[.][4..7] = cols 64+tx*4..
            float4 bA = *(const float4*)&Ws[k * 132 + tx * 4];
            float4 bB = *(const float4*)&Ws[k * 132 + 64 + tx * 4];
            float a0 = a0p[k], a1 = a1p[k], a2 = a2p[k], a3 = a3p[k];
            acc[0][0] += a0 * bA.x; acc[0][1] += a0 * bA.y; acc[0][2] += a0 * bA.z; acc[0][3] += a0 * bA.w;
            acc[0][4] += a0 * bB.x; acc[0][5] += a0 * bB.y; acc[0][6] += a0 * bB.z; acc[0][7] += a0 * bB.w;
            acc[1][0] += a1 * bA.x; acc[1][1] += a1 * bA.y; acc[1][2] += a1 * bA.z; acc[1][3] += a1 * bA.w;
            acc[1][4] += a1 * bB.x; acc[1][5] += a1 * bB.y; acc[1][6] += a1 * bB.z; acc[1][7] += a1 * bB.w;
            acc[2][0] += a2 * bA.x; acc[2][1] += a2 * bA.y; acc[2][2] += a2 * bA.z; acc[2][3] += a2 * bA.w;
            acc[2][4] += a2 * bB.x; acc[2][5] += a2 * bB.y; acc[2][6] += a2 * bB.z; acc[2][7] += a2 * bB.w;
            acc[3][0] += a3 * bA.x; acc[3][1] += a3 * bA.y; acc[3][2] += a3 * bA.z; acc[3][3] += a3 * bA.w;
            acc[3][4] += a3 * bB.x; acc[3][5] += a3 * bB.y; acc[3][6] += a3 * bB.z; acc[3][7] += a3 * bB.w;
        }
        __syncthreads();
    }

    // columns owned: tx*4.. (A half) and 64+tx*4.. (B half)
    float4 g1a = ((const float4*)g1)[tx], g1b = ((const float4*)g1)[16 + tx];
    float4 b1a = ((const float4*)b1)[tx], b1b = ((const float4*)b1)[16 + tx];
    float* Hs = Ws;
#pragma unroll
    for (int i = 0; i < 4; ++i) {
        int row = ty * 4 + i;
        float4 hA, hB;
        hA.x = fmaxf(acc[i][0] * g1a.x + b1a.x, 0.f);
        hA.y = fmaxf(acc[i][1] * g1a.y + b1a.y, 0.f);
        hA.z = fmaxf(acc[i][2] * g1a.z + b1a.z, 0.f);
        hA.w = fmaxf(acc[i][3] * g1a.w + b1a.w, 0.f);
        hB.x = fmaxf(acc[i][4] * g1b.x + b1b.x, 0.f);
        hB.y = fmaxf(acc[i][5] * g1b.y + b1b.y, 0.f);
        hB.z = fmaxf(acc[i][6] * g1b.z + b1b.z, 0.f);
        hB.w = fmaxf(acc[i][7] * g1b.w + b1b.w, 0.f);
        *(float4*)&Hs[row * 132 + tx * 4] = hA;
        *(float4*)&Hs[row * 132 + 64 + tx * 4] = hB;
    }
    __syncthreads();

    const int r = tid >> 2;
    const int p = tid & 3;
    float a2[10];
#pragma unroll
    for (int c = 0; c < 10; ++c) a2[c] = 0.f;
    for (int kk = 0; kk < 32; ++kk) {
        int k = kk * 4 + p;
        float hv = Hs[r * 132 + k];
#pragma unroll
        for (int c = 0; c < 10; ++c) a2[c] += hv * W2s[k * 10 + c];
    }
#pragma unroll
    for (int c = 0; c < 10; ++c) {
        a2[c] += __shfl_xor(a2[c], 1);
        a2[c] += __shfl_xor(a2[c], 2);
    }
    if (p == 0) {
        int m = m0 + r;
        float best = -INFINITY;
        int bi = 0;
#pragma unroll
        for (int c = 0; c < 10; ++c) {
            float s = a2[c] + b2[c];
            out_s10[(size_t)m * 10 + c] = s;
            if (s > best) { best = s; bi = c; }
        }
        out_heat[m] = best;
        cls[m] = bi;
        int b = m / NF;
        unsigned i = (unsigned)(m - b * NF);
        float sig = 1.0f / (1.0f + expf(-best));
        keys[m] = ((unsigned long long)ordf(sig) << 32) | (unsigned)(~i);
    }
}

// ---------------------------------------------------------------------------
// K2: blocks 0-1 = topk. R2 structure (plain LDS atomics — R4's ballot
// aggregation reverted: keys span ~100 distinct bins so waves hold ~50-64
// distinct values and the ballot loop serializes). Kept from R4: bins16 LDS
// cache so the collect pass scans LDS u16s and gathers only candidate keys
// from global (no second 160 KB pass). New: paired ulonglong2 key loads.
// Blocks 2-33 = grid SCAN+SCATTER (unchanged).
// ---------------------------------------------------------------------------
#define H1BINS 16384

__global__ __launch_bounds__(1024) void mid_kernel(
    const unsigned long long* __restrict__ keys,
    const int* __restrict__ cls,
    const int* __restrict__ fcoords,
    float* __restrict__ out1,
    float* __restrict__ out4,
    int* __restrict__ tki,
    float* __restrict__ keyworld,
    const int* __restrict__ sca, const int* __restrict__ scb,
    const int* __restrict__ bh,
    int* __restrict__ gstart,
    float2* __restrict__ pts, int* __restrict__ pidx)
{
    __shared__ unsigned h[H1BINS];            // 64 KB
    __shared__ unsigned sA[1024], sB[1024];   // 8 KB scan buffers
    __shared__ unsigned long long list[1024]; // 8 KB
    __shared__ unsigned short bins16[NF];     // 40 KB cached bin ids
    __shared__ unsigned chunk_s, aboveC_s, T1_s, aboveT1_s, cand_s, thr_s, cnt_s;
    const int tid = threadIdx.x;
    const int blk = blockIdx.x;

    if (blk >= 2) {
        // ---- grid scan + scatter for slice (sb, j) ----
        const int idx = blk - 2;            // 0..31
        const int sb = idx >> 3;            // 0..3
        const int j = idx & (GB - 1);       // 0..7
        const int s = sb >> 1, b = sb & 1;
        const int n = s ? CELLS_B : CELLS_A;
        const int nc = s ? NCB : NCA;
        const float stride = s ? 8.0f : 4.0f;
        const float inv_h = s ? (1.0f / HB) : (1.0f / HA);
        const int stb = STB(s, b);
        const int2* sc = ((const int2*)(s ? scb : sca)) + (size_t)b * NS;
        const int4* scv = (const int4*)sc;
        const size_t pbase = ((size_t)s * BB + b) * NS;
        const int* bhsb = bh + (sb << 14);  // sb * GB * 2048
        int* tot = (int*)h;                 // [0..2047]
        int* cur = ((int*)h) + 2048;        // pre, then cursor  [2048..4095]
        int* scn0 = (int*)sA;
        int* scn1 = (int*)sB;

        for (int c = tid; c < 2048; c += 1024) {
            int t = 0, pr = 0;
#pragma unroll
            for (int g = 0; g < GB; ++g) {
                int v = bhsb[(g << 11) + c];
                t += v;
                if (g < j) pr += v;
            }
            tot[c] = t;
            cur[c] = pr;                    // pre-sum for this block's cursor
        }
        __syncthreads();
        // exclusive scan over tot[0..n-1]; thread owns cells 2t, 2t+1
        const int i0 = tid * 2, i1 = tid * 2 + 1;
        int c0 = (i0 < n) ? tot[i0] : 0;
        int c1 = (i1 < n) ? tot[i1] : 0;
        scn0[tid] = c0 + c1;
        __syncthreads();
        int* srcp = scn0; int* dstp = scn1;
        for (int off = 1; off < 1024; off <<= 1) {
            int v = srcp[tid];
            if (tid >= off) v += srcp[tid - off];
            dstp[tid] = v;
            __syncthreads();
            int* t = srcp; srcp = dstp; dstp = t;
        }
        const int excl = (tid == 0) ? 0 : srcp[tid - 1];
        if (i0 < n) {
            if (j == 0) gstart[stb + i0] = excl;
            cur[i0] += excl;
        }
        if (i1 < n) {
            if (j == 0) gstart[stb + i1] = excl + c0;
            cur[i1] += excl + c0;
        }
        if (j == 0 && tid == 0) gstart[stb + n] = NS;
        __syncthreads();
        // scatter this block's slice
        for (int p = j * SLICE4 + tid; p < (j + 1) * SLICE4; p += 1024) {
            int4 v = scv[p];
            float sx0, sy0, sx1, sy1;
            int cell0 = cell_of(v.x, v.y, stride, inv_h, nc, sx0, sy0);
            int cell1 = cell_of(v.z, v.w, stride, inv_h, nc, sx1, sy1);
            int pos0 = atomicAdd(&cur[cell0], 1);
            int pos1 = atomicAdd(&cur[cell1], 1);
            pts[pbase + pos0] = make_float2(sx0, sy0);
            pidx[pbase + pos0] = p * 2;
            pts[pbase + pos1] = make_float2(sx1, sy1);
            pidx[pbase + pos1] = p * 2 + 1;
        }
        return;
    }

    // ---- topk for batch b = blk ----
    const int b = blk;
    const unsigned long long* kb = keys + (size_t)b * NF;
    const unsigned K = NK;

    for (int i = tid; i < H1BINS; i += 1024) h[i] = 0u;
    __syncthreads();
    // paired key loads; cache 14-bit bins in LDS; plain LDS atomics
    for (int i2 = tid; i2 < NF / 2; i2 += 1024) {
        ulonglong2 kv = ((const ulonglong2*)kb)[i2];
        unsigned b0 = (unsigned)(kv.x >> 50);
        unsigned b1_ = (unsigned)(kv.y >> 50);
        bins16[2 * i2] = (unsigned short)b0;
        bins16[2 * i2 + 1] = (unsigned short)b1_;
        atomicAdd(&h[b0], 1u);
        atomicAdd(&h[b1_], 1u);
    }
    __syncthreads();
    unsigned ck = 0;
    {
        int base = tid * 16;
#pragma unroll
        for (int j = 0; j < 16; ++j) ck += h[base + j];
        sA[tid] = ck;
    }
    __syncthreads();
    // inclusive suffix scan over 1024 chunk sums
    unsigned* srcp = sA; unsigned* dstp = sB;
    for (int off = 1; off < 1024; off <<= 1) {
        unsigned v = srcp[tid];
        if (tid + off < 1024) v += srcp[tid + off];
        dstp[tid] = v;
        __syncthreads();
        unsigned* t = srcp; srcp = dstp; dstp = t;
    }
    {
        unsigned suf = srcp[tid];
        unsigned above = suf - ck;
        if (above < K && K <= suf) { chunk_s = (unsigned)tid; aboveC_s = above; }
    }
    __syncthreads();
    if (tid == 0) {
        int bin = (int)chunk_s * 16 + 15;
        unsigned acc = aboveC_s;
        for (;; --bin) { if (acc + h[bin] >= K) break; acc += h[bin]; }
        T1_s = (unsigned)bin;
        aboveT1_s = acc;
        cand_s = acc + h[bin];
        cnt_s = 0u;
    }
    __syncthreads();
    const unsigned T1 = T1_s;

    if (cand_s <= 1024u) {
        // collect via cached LDS bins (u32 = 2 bins per read); gather only
        // candidate keys (<=1024 total) from global
        const unsigned* b32v = (const unsigned*)bins16;
        for (int i2 = tid; i2 < NF / 2; i2 += 1024) {
            unsigned pk = b32v[i2];
            if ((pk & 0xFFFFu) >= T1) {
                unsigned pos = atomicAdd(&cnt_s, 1u);
                if (pos < 1024u) list[pos] = kb[2 * i2];
            }
            if ((pk >> 16) >= T1) {
                unsigned pos = atomicAdd(&cnt_s, 1u);
                if (pos < 1024u) list[pos] = kb[2 * i2 + 1];
            }
        }
    } else {
        // fallback: refine to 24-bit threshold (rare: >1024 keys in one bin)
        const unsigned K2 = K - aboveT1_s;
        h[tid] = 0u;
        __syncthreads();
#pragma unroll 4
        for (int i = tid; i < NF; i += 1024) {
            unsigned long long key = kb[i];
            if ((unsigned)(key >> 50) == T1)
                atomicAdd(&h[(unsigned)(key >> 40) & 1023u], 1u);
        }
        __syncthreads();
        unsigned hb = h[tid];
        sA[tid] = hb;
        __syncthreads();
        unsigned* s2 = sA; unsigned* d2 = sB;
        for (int off = 1; off < 1024; off <<= 1) {
            unsigned v = s2[tid];
            if (tid + off < 1024) v += s2[tid + off];
            d2[tid] = v;
            __syncthreads();
            unsigned* t = s2; s2 = d2; d2 = t;
        }
        {
            unsigned suf = s2[tid];
            unsigned above = suf - hb;
            if (above < K2 && K2 <= suf) thr_s = (T1 << 10) | (unsigned)tid;
        }
        __syncthreads();
        const unsigned thr24 = thr_s;
#pragma unroll 4
        for (int i = tid; i < NF; i += 1024) {
            unsigned long long key = kb[i];
            if ((unsigned)(key >> 40) >= thr24) {
                unsigned pos = atomicAdd(&cnt_s, 1u);
                if (pos < 1024u) list[pos] = key;
            }
        }
    }
    __syncthreads();
    const int cc = (int)(cnt_s > 1024u ? 1024u : cnt_s);

    // exhaustive ranking: keys unique -> exact permutation, no barriers
    if (tid < cc) {
        unsigned long long mykey = list[tid];
        unsigned r = 0;
#pragma unroll 8
        for (int j = 0; j < cc; ++j) r += (list[j] > mykey) ? 1u : 0u;
        if (r < (unsigned)NK) {
            int idx = (int)(~(unsigned)(mykey & 0xFFFFFFFFull));
            tki[b * NK + (int)r] = idx;
            int c0 = fcoords[((size_t)b * NF + idx) * 2 + 0];
            int c1 = fcoords[((size_t)b * NF + idx) * 2 + 1];
            size_t o = (size_t)(b * NK + (int)r);
            out1[o * 3 + 0] = (float)b;
            out1[o * 3 + 1] = (float)c0;
            out1[o * 3 + 2] = (float)c1;
            float wx = __fadd_rn(__fmul_rn(__fmul_rn(__fadd_rn((float)c0, 0.5f), 8.0f), 0.075f), -54.0f);
            float wy = __fadd_rn(__fmul_rn(__fmul_rn(__fadd_rn((float)c1, 0.5f), 8.0f), 0.075f), -54.0f);
            keyworld[o * 2 + 0] = wx;
            keyworld[o * 2 + 1] = wy;
            out4[o] = (float)cls[(size_t)b * NF + idx];
        }
    }
}

// ---------------------------------------------------------------------------
// K3: grid-accelerated radius-KNN (unchanged).
// ---------------------------------------------------------------------------
__global__ __launch_bounds__(256) void knn_kernel(
    const float* __restrict__ sfa, const float* __restrict__ sfb,
    const int* __restrict__ gstart,
    const float2* __restrict__ pts, const int* __restrict__ pidx,
    const float* __restrict__ knn_w,
    const float* __restrict__ knn_b,
    const float* __restrict__ keyworld,
    float* __restrict__ mf)
{
    __shared__ unsigned long long list[1024];
    __shared__ float psum[128];
    __shared__ unsigned cnt_s;
    const int tid = threadIdx.x;
    const int blk = blockIdx.x;
    const int s = blk / (BB * NK);
    const int rest = blk % (BB * NK);
    const int b = rest / NK;
    const int r = rest % NK;
    const float* sfeat = s ? sfb : sfa;
    const float r2 = s ? (float)(4.8 * 4.8) : (float)(2.4 * 2.4);
    const float inv_h = s ? (1.0f / HB) : (1.0f / HA);
    const int nc = s ? NCB : NCA;
    const int stb = STB(s, b);
    const size_t pbase = ((size_t)s * BB + b) * NS;

    if (tid == 0) cnt_s = 0u;
    __syncthreads();
    const float kx = keyworld[((size_t)b * NK + r) * 2 + 0];
    const float ky = keyworld[((size_t)b * NK + r) * 2 + 1];
    int cx = (int)floorf((kx + 54.0f) * inv_h);
    int cy = (int)floorf((ky + 54.0f) * inv_h);
    cx = min(max(cx, 0), nc - 1);
    cy = min(max(cy, 0), nc - 1);
    const int c0 = max(cx - 1, 0), c1 = min(cx + 1, nc - 1);
    const int cy0 = max(cy - 1, 0), cy1 = min(cy + 1, nc - 1);

    for (int cyy = cy0; cyy <= cy1; ++cyy) {
        int lo = gstart[stb + cyy * nc + c0];
        int hi = gstart[stb + cyy * nc + c1 + 1];
        for (int p = lo + tid; p < hi; p += 256) {
            float2 w = pts[pbase + p];
            float dx = __fsub_rn(kx, w.x);
            float dy = __fsub_rn(ky, w.y);
            float d2 = __fadd_rn(__fmul_rn(dx, dx), __fmul_rn(dy, dy));
            if (d2 <= r2) {
                unsigned pos = atomicAdd(&cnt_s, 1u);
                if (pos < 1024u)
                    list[pos] = ((unsigned long long)__float_as_uint(d2) << 32)
                              | (unsigned)pidx[pbase + p];
            }
        }
    }
    __syncthreads();
    int cc = (int)cnt_s;
    if (cc > 1024) cc = 1024;
    int n2 = 16;
    while (n2 < cc) n2 <<= 1;
    for (int i = tid; i < n2; i += 256)
        if (i >= cc) list[i] = ~0ull;
    __syncthreads();
    for (int kk = 2; kk <= n2; kk <<= 1) {
        for (int j = kk >> 1; j > 0; j >>= 1) {
            for (int i = tid; i < n2; i += 256) {
                int ixj = i ^ j;
                if (ixj > i) {
                    unsigned long long a = list[i], bv = list[ixj];
                    bool up = ((i & kk) == 0);
                    bool sw = up ? (a > bv) : (a < bv);
                    if (sw) { list[i] = bv; list[ixj] = a; }
                }
            }
            __syncthreads();
        }
    }
    {
        int K = cc < KNN ? cc : KNN;
        int col = tid & 127, half = tid >> 7;
        float acc = 0.f;
        int k0 = half * 8, k1 = min(K, half * 8 + 8);
        for (int k = k0; k < k1; ++k) {
            unsigned i = (unsigned)(list[k] & 0xFFFFFFFFull);
            acc += knn_w[s * 16 + k] * sfeat[((size_t)b * NS + i) * CH + col];
        }
        if (half) psum[col] = acc;
        __syncthreads();
        if (!half)
            mf[(((size_t)s * BB + b) * NK + r) * CH + col] = knn_b[s] + acc + psum[col];
    }
}

// ---------------------------------------------------------------------------
// K4: fuse MLP (unchanged: direct L2-resident float4 weight loads,
// 8-16 in flight, transposed activations, split-K tree reduce).
// ---------------------------------------------------------------------------
__global__ __launch_bounds__(1024) void fuse_kernel(
    const float* __restrict__ ffeat,
    const int* __restrict__ tki,
    const float* __restrict__ kw_w1, const float* __restrict__ kw_g1,
    const float* __restrict__ kw_b1, const float* __restrict__ kw_w2,
    const float* __restrict__ kw_b2,
    const float* __restrict__ fuse_w1, const float* __restrict__ fuse_g1,
    const float* __restrict__ fuse_b1, const float* __restrict__ fuse_w2,
    const float* __restrict__ fuse_b2,
    const float* __restrict__ mf,
    float* __restrict__ out0)
{
    __shared__ float pL[16384];     // 64 KB split-K partials
    __shared__ float xsT[512];      // x transposed [k][key]
    __shared__ float mfs[1024];     // [src][key][c]
    __shared__ float fusedvT[1024]; // [k][key]
    __shared__ float h2sT[1024];    // [k][key]
    __shared__ float prm[964];      // kw_g1|kw_b1|kw_w2|kw_b2|fg1|fb1|fb2
    __shared__ float hsX[256];      // kw hidden [key][k]
    __shared__ float p2[96];
    __shared__ float l3[12];
    __shared__ float wsm[8];
    __shared__ int idxs[KPB], bs[KPB], rs[KPB];
    const int tid = threadIdx.x;
    const int f0 = blockIdx.x * KPB;

    if (tid < 964) {
        float v;
        if (tid < 64)       v = kw_g1[tid];
        else if (tid < 128) v = kw_b1[tid - 64];
        else if (tid < 320) v = kw_w2[tid - 128];
        else if (tid < 323) v = kw_b2[tid - 320];
        else if (tid < 324) v = 0.f;
        else if (tid < 580) v = fuse_g1[tid - 324];
        else if (tid < 836) v = fuse_b1[tid - 580];
        else                v = fuse_b2[tid - 836];
        prm[tid] = v;
    }
    if (tid < KPB) {
        int flat = f0 + tid;
        int b = flat / NK;
        bs[tid] = b;
        rs[tid] = flat - b * NK;
        idxs[tid] = tki[flat];
    }
    __syncthreads();

    if (tid < 128) {
        int key = tid >> 5, c4 = tid & 31;
        float4 v = ((const float4*)(ffeat + ((size_t)bs[key] * NF + idxs[key]) * CH))[c4];
        xsT[(c4 * 4 + 0) * 4 + key] = v.x;
        xsT[(c4 * 4 + 1) * 4 + key] = v.y;
        xsT[(c4 * 4 + 2) * 4 + key] = v.z;
        xsT[(c4 * 4 + 3) * 4 + key] = v.w;
    }
    if (tid < 256) {
        int ss = tid >> 7, key = (tid >> 5) & 3, c4 = tid & 31;
        float4 v = ((const float4*)(mf + (((size_t)ss * BB + bs[key]) * NK + rs[key]) * CH))[c4];
        *(float4*)&mfs[ss * 512 + key * 128 + c4 * 4] = v;
    }
    __syncthreads();

    if (tid < 256) {
        const int og = tid & 15, kseg = tid >> 4;
        float4 wr[8];
#pragma unroll
        for (int m = 0; m < 8; ++m)
            wr[m] = ((const float4*)kw_w1)[(kseg * 8 + m) * 16 + og];
        float4 a0 = {0, 0, 0, 0}, a1 = {0, 0, 0, 0}, a2 = {0, 0, 0, 0}, a3 = {0, 0, 0, 0};
#pragma unroll
        for (int m = 0; m < 8; ++m) {
            float4 f4 = *(const float4*)&xsT[(kseg * 8 + m) * 4];
            fma4(a0, f4.x, wr[m]);
            fma4(a1, f4.y, wr[m]);
            fma4(a2, f4.z, wr[m]);
            fma4(a3, f4.w, wr[m]);
        }
        *(float4*)&pL[(kseg * 4 + 0) * 64 + og * 4] = a0;
        *(float4*)&pL[(kseg * 4 + 1) * 64 + og * 4] = a1;
        *(float4*)&pL[(kseg * 4 + 2) * 64 + og * 4] = a2;
        *(float4*)&pL[(kseg * 4 + 3) * 64 + og * 4] = a3;
    }
    __syncthreads();
    if (tid < 256) {
        int out = tid >> 2, key = tid & 3;
        float s = 0.f;
#pragma unroll
        for (int ks = 0; ks < 16; ++ks) s += pL[(ks * 4 + key) * 64 + out];
        float t = s * prm[out] + prm[64 + out];
        hsX[key * 64 + out] = t > 0.f ? t : 0.f;
    }
    __syncthreads();
    if (tid < 96) {
        int key = tid / 24, rr = tid % 24, out = rr >> 3, seg = rr & 7;
        float acc = 0.f;
#pragma unroll
        for (int m = 0; m < 8; ++m) {
            int k = seg * 8 + m;
            acc += hsX[key * 64 + k] * prm[128 + k * 3 + out];
        }
        p2[(key * 3 + out) * 8 + seg] = acc;
    }
    __syncthreads();
    if (tid < 12) {
        int key = tid / 3, out = tid % 3;
        float s = 0.f;
#pragma unroll
        for (int j = 0; j < 8; ++j) s += p2[(key * 3 + out) * 8 + j];
        l3[key * 3 + out] = s + prm[320 + out];
    }
    __syncthreads();
    if (tid < KPB) {
        float l0 = l3[tid * 3], l1 = l3[tid * 3 + 1], l2 = l3[tid * 3 + 2];
        float m = fmaxf(l0, fmaxf(l1, l2));
        float e0 = expf(l0 - m), e1 = expf(l1 - m), e2 = expf(l2 - m);
        float sum = e0 + e1 + e2;
        wsm[tid * 2 + 0] = e0 / sum;
        wsm[tid * 2 + 1] = e1 / sum;
    }
    __syncthreads();

    {
        int c = tid >> 2, key = tid & 3;
        float w0 = wsm[key * 2], w1_ = wsm[key * 2 + 1];
        float val;
        if (c < 128) {
            float xv_ = xsT[c * 4 + key];
            float m0 = mfs[key * 128 + c];
            float m1 = mfs[512 + key * 128 + c];
            float kv = w0 * xv_;
            float kv2 = w1_ * kv;
            val = kv * m0 + kv2 * m1;
        } else {
            float xv_ = xsT[(c - 128) * 4 + key];
            val = w1_ * (w0 * xv_);
        }
        fusedvT[tid] = val;
    }
    __syncthreads();

    {
        const int og = tid & 63, kseg = tid >> 6;
        const float4* w1v = (const float4*)fuse_w1;
        float4 wr[16];
#pragma unroll
        for (int m = 0; m < 16; ++m)
            wr[m] = w1v[(kseg * 16 + m) * 64 + og];
        float4 a0 = {0, 0, 0, 0}, a1 = {0, 0, 0, 0}, a2 = {0, 0, 0, 0}, a3 = {0, 0, 0, 0};
#pragma unroll
        for (int m = 0; m < 16; ++m) {
            float4 f4 = *(const float4*)&fusedvT[(kseg * 16 + m) * 4];
            fma4(a0, f4.x, wr[m]);
            fma4(a1, f4.y, wr[m]);
            fma4(a2, f4.z, wr[m]);
            fma4(a3, f4.w, wr[m]);
        }
        *(float4*)&pL[(kseg * 4 + 0) * 256 + og * 4] = a0;
        *(float4*)&pL[(kseg * 4 + 1) * 256 + og * 4] = a1;
        *(float4*)&pL[(kseg * 4 + 2) * 256 + og * 4] = a2;
        *(float4*)&pL[(kseg * 4 + 3) * 256 + og * 4] = a3;
    }
    __syncthreads();
    {
        int out = tid >> 2, key = tid & 3;
        float s = 0.f;
#pragma unroll
        for (int ks = 0; ks < 16; ++ks) s += pL[(ks * 4 + key) * 256 + out];
        float t = s * prm[324 + out] + prm[580 + out];
        h2sT[out * 4 + key] = t > 0.f ? t : 0.f;
    }
    __syncthreads();

    {
        const int og2 = tid & 31, kseg2 = tid >> 5;
        const float4* w2v = (const float4*)fuse_w2;
        float4 wr[8];
#pragma unroll
        for (int m = 0; m < 8; ++m)
            wr[m] = w2v[(kseg2 * 8 + m) * 32 + og2];
        float4 a0 = {0, 0, 0, 0}, a1 = {0, 0, 0, 0}, a2 = {0, 0, 0, 0}, a3 = {0, 0, 0, 0};
#pragma unroll
        for (int m = 0; m < 8; ++m) {
            float4 f4 = *(const float4*)&h2sT[(kseg2 * 8 + m) * 4];
            fma4(a0, f4.x, wr[m]);
            fma4(a1, f4.y, wr[m]);
            fma4(a2, f4.z, wr[m]);
            fma4(a3, f4.w, wr[m]);
        }
        *(float4*)&pL[(kseg2 * 4 + 0) * 128 + og2 * 4] = a0;
        *(float4*)&pL[(kseg2 * 4 + 1) * 128 + og2 * 4] = a1;
        *(float4*)&pL[(kseg2 * 4 + 2) * 128 + og2 * 4] = a2;
        *(float4*)&pL[(kseg2 * 4 + 3) * 128 + og2 * 4] = a3;
    }
    __syncthreads();
    if (tid < 512) {
        int out = tid >> 2, key = tid & 3;
        float s = prm[836 + out];
#pragma unroll
        for (int ks = 0; ks < 32; ++ks) s += pL[(ks * 4 + key) * 128 + out];
        out0[((size_t)bs[key] * NK + rs[key]) * CH + out] = s;
    }
}

extern "C" void kernel_launch(void* const* d_in, const int* in_sizes, int n_in,
                              void* d_out, int out_size, void* d_ws, size_t ws_size,
                              hipStream_t stream)
{
    const float* fusion_feat = (const float*)d_in[0];
    const float* src_feat_a  = (const float*)d_in[1];
    const float* src_feat_b  = (const float*)d_in[2];
    const float* heat_w1 = (const float*)d_in[3];
    const float* heat_g1 = (const float*)d_in[4];
    const float* heat_b1 = (const float*)d_in[5];
    const float* heat_w2 = (const float*)d_in[6];
    const float* heat_b2 = (const float*)d_in[7];
    const float* knn_w   = (const float*)d_in[8];
    const float* knn_b   = (const float*)d_in[9];
    const float* kw_w1   = (const float*)d_in[10];
    const float* kw_g1   = (const float*)d_in[11];
    const float* kw_b1   = (const float*)d_in[12];
    const float* kw_w2   = (const float*)d_in[13];
    const float* kw_b2   = (const float*)d_in[14];
    const float* fuse_w1 = (const float*)d_in[15];
    const float* fuse_g1 = (const float*)d_in[16];
    const float* fuse_b1 = (const float*)d_in[17];
    const float* fuse_w2 = (const float*)d_in[18];
    const float* fuse_b2 = (const float*)d_in[19];
    const int* fusion_coords = (const int*)d_in[20];
    const int* src_coords_a  = (const int*)d_in[21];
    const int* src_coords_b  = (const int*)d_in[22];

    float* out = (float*)d_out;
    char* ws = (char*)d_ws;
    int* cls = (int*)(ws + WS_CLS);
    int* tki = (int*)(ws + WS_TKI);
    float* keyworld = (float*)(ws + WS_KW);
    float* mf = (float*)(ws + WS_MF);
    unsigned long long* keys = (unsigned long long*)(ws + WS_KEYS);
    int* bh = (int*)(ws + WS_BH);
    int* gstart = (int*)(ws + WS_GSTART);
    float2* pts = (float2*)(ws + WS_PTS);
    int* pidx = (int*)(ws + WS_PIDX);

    heat_kernel<<<(BB * NF) / 64 + 4 * GB, 256, 0, stream>>>(
        fusion_feat, heat_w1, heat_g1, heat_b1, heat_w2, heat_b2,
        out + OUT2_OFF, out + OUT3_OFF, cls, keys,
        src_coords_a, src_coords_b, bh);

    mid_kernel<<<2 + 4 * GB, 1024, 0, stream>>>(
        keys, cls, fusion_coords,
        out + OUT1_OFF, out + OUT4_OFF, tki, keyworld,
        src_coords_a, src_coords_b, bh, gstart, pts, pidx);

    knn_kernel<<<2 * BB * NK, 256, 0, stream>>>(
        src_feat_a, src_feat_b, gstart, pts, pidx,
        knn_w, knn_b, keyworld, mf);

    fuse_kernel<<<(BB * NK) / KPB, 1024, 0, stream>>>(
        fusion_feat, tki, kw_w1, kw_g1, kw_b1, kw_w2, kw_b2,
        fuse_w1, fuse_g1, fuse_b1, fuse_w2, fuse_b2, mf, out + OUT0_OFF);
}

// Round 6
// 229.631 us; speedup vs baseline: 1.4287x; 1.0116x over previous
//
#include <hip/hip_runtime.h>
#include <math.h>

#define BB 2
#define NF 20000
#define NS 30000
#define CH 128
#define NK 500
#define KNN 16
#define KPB 4

// grid params: cell = 1.001 * radius (margin vs float boundary rounding)
#define HA 2.4024f
#define HB 4.8048f
#define NCA 45
#define NCB 23
#define CELLS_A 2025
#define CELLS_B 529

// multi-block counting sort for the spatial grid
#define GB 8                 // count/scatter blocks per (s,b)
#define SLICE 3750           // NS / GB points per block
#define SLICE4 1875          // int4 (2-point) loads per slice

// output offsets (floats, concatenated in return order)
#define OUT0_OFF 0           // out          (B*NK*128) = 128000
#define OUT1_OFF 128000      // key_voxel_indices (B*NK*3) = 3000
#define OUT2_OFF 131000      // heat_scores  (B*NF) = 40000
#define OUT3_OFF 171000      // scores10     (B*NF*10) = 400000
#define OUT4_OFF 571000      // key_class    (B*NK) = 1000

// workspace offsets (bytes)
#define WS_CLS   0           // int32  x 40000
#define WS_TKI   160000      // int32  x 1000
#define WS_KW    164000      // float  x 2000
#define WS_MF    172000      // float  x 256000 (1,024,000 B)
#define WS_KEYS  WS_MF       // u64 x 40000 overlays mf head (temporally disjoint)
#define WS_BH    492000      // int x 65536: per-block hists [sb][g][2048], overlays mf tail
#define WS_GSTART 1196000    // int x 5112 (cell starts, +1 per (s,b))
#define WS_PTS    1236880    // float2 x 120000 (sorted world coords)
#define WS_PIDX   2196880    // int x 120000 (sorted original indices)

#define STB(s,b)  ((s) ? (4052 + (b) * 530) : ((b) * 2026))

__device__ __forceinline__ void fma4(float4& acc, float sc, const float4& wv) {
    acc.x += sc * wv.x; acc.y += sc * wv.y;
    acc.z += sc * wv.z; acc.w += sc * wv.w;
}

__device__ __forceinline__ unsigned ordf(float s) {
    unsigned u = __float_as_uint(s);
    return (u & 0x80000000u) ? ~u : (u | 0x80000000u);
}

// identical arithmetic in count and scatter phases (bitwise-consistent cells)
__device__ __forceinline__ int cell_of(int cxi, int cyi, float stride, float inv_h,
                                       int nc, float& sx, float& sy)
{
    sx = __fadd_rn(__fmul_rn(__fmul_rn(__fadd_rn((float)cxi, 0.5f), stride), 0.075f), -54.0f);
    sy = __fadd_rn(__fmul_rn(__fmul_rn(__fadd_rn((float)cyi, 0.5f), stride), 0.075f), -54.0f);
    int cx = (int)floorf((sx + 54.0f) * inv_h);
    int cy = (int)floorf((sy + 54.0f) * inv_h);
    cx = min(max(cx, 0), nc - 1);
    cy = min(max(cy, 0), nc - 1);
    return cy * nc + cx;
}

// 1024-thread inclusive scan: wave shfl scan + 16 wave-sum exchange.
// 2 barriers (vs 20 for the old ping-pong scan). Returns inclusive prefix,
// writes grand total. ws must be a 16-entry LDS array.
__device__ __forceinline__ unsigned block_scan_incl(unsigned v, int tid,
                                                    volatile unsigned* ws,
                                                    unsigned* total)
{
    const int lane = tid & 63, wid = tid >> 6;
    unsigned p = v;
#pragma unroll
    for (int off = 1; off < 64; off <<= 1) {
        unsigned t = (unsigned)__shfl_up((int)p, off);
        if (lane >= off) p += t;
    }
    __syncthreads();                 // protect ws against a previous scan's readers
    if (lane == 63) ws[wid] = p;
    __syncthreads();
    unsigned woff = 0, tot = 0;
#pragma unroll
    for (int w = 0; w < 16; ++w) {
        unsigned s = ws[w];
        tot += s;
        if (w < wid) woff += s;
    }
    *total = tot;
    return p + woff;
}

// ---------------------------------------------------------------------------
// K1: blocks 0-31 = grid COUNT phase (8 blocks per (s,b), private per-block
// histograms); blocks 32+ = heat MLP SGEMM.
// This round: K-chunk 64->32 and a unioned LDS pool (GEMM: As 64x36 +
// Ws 32x132 = 26 KB; epilogue: Hs 64x132 = 33 KB reuses the pool) -> ~38 KB
// total -> 4 blocks/CU (was 2): all 657 blocks resident in one round (no
// straggler tail) and 16 waves/CU of latency hiding.
// ---------------------------------------------------------------------------
__global__ __launch_bounds__(256) void heat_kernel(
    const float* __restrict__ x,
    const float* __restrict__ w1,
    const float* __restrict__ g1, const float* __restrict__ b1,
    const float* __restrict__ w2,
    const float* __restrict__ b2,
    float* __restrict__ out_heat,
    float* __restrict__ out_s10,
    int* __restrict__ cls,
    unsigned long long* __restrict__ keys,
    const int* __restrict__ sca, const int* __restrict__ scb,
    int* __restrict__ bh)
{
    __shared__ float Pool[8448];    // GEMM: As=[0,2304) s36, Ws=[2304,6528) s132 ; Epi: Hs=[0,8448) s132
    __shared__ float W2s[1280];
    const int tid = threadIdx.x;

    if (blockIdx.x < 4 * GB) {
        const int gflat = blockIdx.x;
        const int sb = gflat >> 3;          // 0..3
        const int gg = gflat & (GB - 1);    // 0..7
        const int s = sb >> 1, b = sb & 1;
        const float stride = s ? 8.0f : 4.0f;
        const float inv_h = s ? (1.0f / HB) : (1.0f / HA);
        const int nc = s ? NCB : NCA;
        const int2* sc = ((const int2*)(s ? scb : sca)) + (size_t)b * NS;
        const int4* scv = (const int4*)sc;
        int* hist_l = (int*)Pool;           // 2048 ints

        for (int i = tid; i < 2048; i += 256) hist_l[i] = 0;
        __syncthreads();
        for (int p = gg * SLICE4 + tid; p < (gg + 1) * SLICE4; p += 256) {
            int4 v = scv[p];
            float sx, sy;
            int cell0 = cell_of(v.x, v.y, stride, inv_h, nc, sx, sy);
            int cell1 = cell_of(v.z, v.w, stride, inv_h, nc, sx, sy);
            atomicAdd(&hist_l[cell0], 1);
            atomicAdd(&hist_l[cell1], 1);
        }
        __syncthreads();
        int* bhp = bh + (gflat << 11);
        for (int i = tid; i < 2048; i += 256) bhp[i] = hist_l[i];
        return;
    }

    const int m0 = (blockIdx.x - 4 * GB) * 64;
    const int tx = tid & 15;
    const int ty = tid >> 4;
    float* As = Pool;               // 64 rows, stride 36 (32 data + 4 pad)
    float* Ws = Pool + 2304;        // 32 rows, stride 132

    for (int v = tid; v < 1280; v += 256) W2s[v] = w2[v];

    float acc[4][8];
#pragma unroll
    for (int i = 0; i < 4; ++i)
#pragma unroll
        for (int j = 0; j < 8; ++j) acc[i][j] = 0.f;

    const float4* xv = (const float4*)x;
    const float4* w1v = (const float4*)w1;

    for (int kc = 0; kc < 128; kc += 32) {
#pragma unroll
        for (int i = 0; i < 2; ++i) {
            int v = tid + i * 256;
            int row = v >> 3, c4 = v & 7;
            float4 val = xv[(size_t)(m0 + row) * 32 + (kc >> 2) + c4];
            *(float4*)&As[row * 36 + c4 * 4] = val;
        }
#pragma unroll
        for (int i = 0; i < 4; ++i) {
            int v = tid + i * 256;
            int k = v >> 5, c4 = v & 31;
            float4 val = w1v[(size_t)(kc + k) * 32 + c4];
            *(float4*)&Ws[k * 132 + c4 * 4] = val;
        }
        __syncthreads();

        const float* a0p = &As[(ty * 4 + 0) * 36];
        const float* a1p = &As[(ty * 4 + 1) * 36];
        const float* a2p = &As[(ty * 4 + 2) * 36];
        const float* a3p = &As[(ty * 4 + 3) * 36];
#pragma unroll 4
        for (int k = 0; k < 32; ++k) {
            // acc[.][0..3] = hidden cols tx*4.. ; acc[.][4..7] = cols 64+tx*4..
            float4 bA = *(const float4*)&Ws[k * 132 + tx * 4];
            float4 bB = *(const float4*)&Ws[k * 132 + 64 + tx * 4];
            float a0 = a0p[k], a1 = a1p[k], a2 = a2p[k], a3 = a3p[k];
            acc[0][0] += a0 * bA.x; acc[0][1] += a0 * bA.y; acc[0][2] += a0 * bA.z; acc[0][3] += a0 * bA.w;
            acc[0][4] += a0 * bB.x; acc[0][5] += a0 * bB.y; acc[0][6] += a0 * bB.z; acc[0][7] += a0 * bB.w;
            acc[1][0] += a1 * bA.x; acc[1][1] += a1 * bA.y; acc[1][2] += a1 * bA.z; acc[1][3] += a1 * bA.w;
            acc[1][4] += a1 * bB.x; acc[1][5] += a1 * bB.y; acc[1][6] += a1 * bB.z; acc[1][7] += a1 * bB.w;
            acc[2][0] += a2 * bA.x; acc[2][1] += a2 * bA.y; acc[2][2] += a2 * bA.z; acc[2][3] += a2 * bA.w;
            acc[2][4] += a2 * bB.x; acc[2][5] += a2 * bB.y; acc[2][6] += a2 * bB.z; acc[2][7] += a2 * bB.w;
            acc[3][0] += a3 * bA.x; acc[3][1] += a3 * bA.y; acc[3][2] += a3 * bA.z; acc[3][3] += a3 * bA.w;
            acc[3][4] += a3 * bB.x; acc[3][5] += a3 * bB.y; acc[3][6] += a3 * bB.z; acc[3][7] += a3 * bB.w;
        }
        __syncthreads();
    }

    // columns owned: tx*4.. (A half) and 64+tx*4.. (B half)
    float4 g1a = ((const float4*)g1)[tx], g1b = ((const float4*)g1)[16 + tx];
    float4 b1a = ((const float4*)b1)[tx], b1b = ((const float4*)b1)[16 + tx];
    float* Hs = Pool;               // 64 rows, stride 132 (reuses As+Ws space)
#pragma unroll
    for (int i = 0; i < 4; ++i) {
        int row = ty * 4 + i;
        float4 hA, hB;
        hA.x = fmaxf(acc[i][0] * g1a.x + b1a.x, 0.f);
        hA.y = fmaxf(acc[i][1] * g1a.y + b1a.y, 0.f);
        hA.z = fmaxf(acc[i][2] * g1a.z + b1a.z, 0.f);
        hA.w = fmaxf(acc[i][3] * g1a.w + b1a.w, 0.f);
        hB.x = fmaxf(acc[i][4] * g1b.x + b1b.x, 0.f);
        hB.y = fmaxf(acc[i][5] * g1b.y + b1b.y, 0.f);
        hB.z = fmaxf(acc[i][6] * g1b.z + b1b.z, 0.f);
        hB.w = fmaxf(acc[i][7] * g1b.w + b1b.w, 0.f);
        *(float4*)&Hs[row * 132 + tx * 4] = hA;
        *(float4*)&Hs[row * 132 + 64 + tx * 4] = hB;
    }
    __syncthreads();

    const int r = tid >> 2;
    const int p = tid & 3;
    float a2[10];
#pragma unroll
    for (int c = 0; c < 10; ++c) a2[c] = 0.f;
    for (int kk = 0; kk < 32; ++kk) {
        int k = kk * 4 + p;
        float hv = Hs[r * 132 + k];
#pragma unroll
        for (int c = 0; c < 10; ++c) a2[c] += hv * W2s[k * 10 + c];
    }
#pragma unroll
    for (int c = 0; c < 10; ++c) {
        a2[c] += __shfl_xor(a2[c], 1);
        a2[c] += __shfl_xor(a2[c], 2);
    }
    if (p == 0) {
        int m = m0 + r;
        float best = -INFINITY;
        int bi = 0;
#pragma unroll
        for (int c = 0; c < 10; ++c) {
            float s = a2[c] + b2[c];
            out_s10[(size_t)m * 10 + c] = s;
            if (s > best) { best = s; bi = c; }
        }
        out_heat[m] = best;
        cls[m] = bi;
        int b = m / NF;
        unsigned i = (unsigned)(m - b * NF);
        float sig = 1.0f / (1.0f + expf(-best));
        keys[m] = ((unsigned long long)ordf(sig) << 32) | (unsigned)(~i);
    }
}

// ---------------------------------------------------------------------------
// K2: blocks 0-1 = topk (plain LDS atomic hist + bins16 cache + paired key
// loads); blocks 2-33 = grid SCAN+SCATTER. All 1024-thread scans replaced by
// wave-shfl scans (2 barriers instead of 20).
// ---------------------------------------------------------------------------
#define H1BINS 16384

__global__ __launch_bounds__(1024) void mid_kernel(
    const unsigned long long* __restrict__ keys,
    const int* __restrict__ cls,
    const int* __restrict__ fcoords,
    float* __restrict__ out1,
    float* __restrict__ out4,
    int* __restrict__ tki,
    float* __restrict__ keyworld,
    const int* __restrict__ sca, const int* __restrict__ scb,
    const int* __restrict__ bh,
    int* __restrict__ gstart,
    float2* __restrict__ pts, int* __restrict__ pidx)
{
    __shared__ unsigned h[H1BINS];            // 64 KB
    __shared__ unsigned long long list[1024]; // 8 KB
    __shared__ unsigned short bins16[NF];     // 40 KB cached bin ids
    __shared__ unsigned wsum[16];             // wave-sum exchange for scans
    __shared__ unsigned chunk_s, aboveC_s, T1_s, aboveT1_s, cand_s, thr_s, cnt_s;
    const int tid = threadIdx.x;
    const int blk = blockIdx.x;

    if (blk >= 2) {
        // ---- grid scan + scatter for slice (sb, j) ----
        const int idx = blk - 2;            // 0..31
        const int sb = idx >> 3;            // 0..3
        const int j = idx & (GB - 1);       // 0..7
        const int s = sb >> 1, b = sb & 1;
        const int n = s ? CELLS_B : CELLS_A;
        const int nc = s ? NCB : NCA;
        const float stride = s ? 8.0f : 4.0f;
        const float inv_h = s ? (1.0f / HB) : (1.0f / HA);
        const int stb = STB(s, b);
        const int2* sc = ((const int2*)(s ? scb : sca)) + (size_t)b * NS;
        const int4* scv = (const int4*)sc;
        const size_t pbase = ((size_t)s * BB + b) * NS;
        const int* bhsb = bh + (sb << 14);  // sb * GB * 2048
        int* tot = (int*)h;                 // [0..2047]
        int* cur = ((int*)h) + 2048;        // pre, then cursor  [2048..4095]

        for (int c = tid; c < 2048; c += 1024) {
            int t = 0, pr = 0;
#pragma unroll
            for (int g = 0; g < GB; ++g) {
                int v = bhsb[(g << 11) + c];
                t += v;
                if (g < j) pr += v;
            }
            tot[c] = t;
            cur[c] = pr;                    // pre-sum for this block's cursor
        }
        __syncthreads();
        // exclusive scan over tot[0..n-1]; thread owns cells 2t, 2t+1
        const int i0 = tid * 2, i1 = tid * 2 + 1;
        int c0 = (i0 < n) ? tot[i0] : 0;
        int c1 = (i1 < n) ? tot[i1] : 0;
        unsigned totsum;
        unsigned P = block_scan_incl((unsigned)(c0 + c1), tid, wsum, &totsum);
        const int excl = (int)P - (c0 + c1);
        if (i0 < n) {
            if (j == 0) gstart[stb + i0] = excl;
            cur[i0] += excl;
        }
        if (i1 < n) {
            if (j == 0) gstart[stb + i1] = excl + c0;
            cur[i1] += excl + c0;
        }
        if (j == 0 && tid == 0) gstart[stb + n] = NS;
        __syncthreads();
        // scatter this block's slice
        for (int p = j * SLICE4 + tid; p < (j + 1) * SLICE4; p += 1024) {
            int4 v = scv[p];
            float sx0, sy0, sx1, sy1;
            int cell0 = cell_of(v.x, v.y, stride, inv_h, nc, sx0, sy0);
            int cell1 = cell_of(v.z, v.w, stride, inv_h, nc, sx1, sy1);
            int pos0 = atomicAdd(&cur[cell0], 1);
            int pos1 = atomicAdd(&cur[cell1], 1);
            pts[pbase + pos0] = make_float2(sx0, sy0);
            pidx[pbase + pos0] = p * 2;
            pts[pbase + pos1] = make_float2(sx1, sy1);
            pidx[pbase + pos1] = p * 2 + 1;
        }
        return;
    }

    // ---- topk for batch b = blk ----
    const int b = blk;
    const unsigned long long* kb = keys + (size_t)b * NF;
    const unsigned K = NK;

    for (int i = tid; i < H1BINS; i += 1024) h[i] = 0u;
    __syncthreads();
    // paired key loads; cache 14-bit bins in LDS; plain LDS atomics
    for (int i2 = tid; i2 < NF / 2; i2 += 1024) {
        ulonglong2 kv = ((const ulonglong2*)kb)[i2];
        unsigned b0 = (unsigned)(kv.x >> 50);
        unsigned b1_ = (unsigned)(kv.y >> 50);
        bins16[2 * i2] = (unsigned short)b0;
        bins16[2 * i2 + 1] = (unsigned short)b1_;
        atomicAdd(&h[b0], 1u);
        atomicAdd(&h[b1_], 1u);
    }
    __syncthreads();
    unsigned ck = 0;
    {
        int base = tid * 16;
#pragma unroll
        for (int j = 0; j < 16; ++j) ck += h[base + j];
    }
    {
        unsigned tot;
        unsigned P = block_scan_incl(ck, tid, wsum, &tot);
        unsigned suf = tot - P + ck;     // inclusive suffix
        unsigned above = tot - P;        // exclusive suffix (chunks after mine)
        if (above < K && K <= suf) { chunk_s = (unsigned)tid; aboveC_s = above; }
    }
    __syncthreads();
    if (tid == 0) {
        int bin = (int)chunk_s * 16 + 15;
        unsigned acc = aboveC_s;
        for (;; --bin) { if (acc + h[bin] >= K) break; acc += h[bin]; }
        T1_s = (unsigned)bin;
        aboveT1_s = acc;
        cand_s = acc + h[bin];
        cnt_s = 0u;
    }
    __syncthreads();
    const unsigned T1 = T1_s;

    if (cand_s <= 1024u) {
        // collect via cached LDS bins (u32 = 2 bins per read); gather only
        // candidate keys (<=1024 total) from global
        const unsigned* b32v = (const unsigned*)bins16;
        for (int i2 = tid; i2 < NF / 2; i2 += 1024) {
            unsigned pk = b32v[i2];
            if ((pk & 0xFFFFu) >= T1) {
                unsigned pos = atomicAdd(&cnt_s, 1u);
                if (pos < 1024u) list[pos] = kb[2 * i2];
            }
            if ((pk >> 16) >= T1) {
                unsigned pos = atomicAdd(&cnt_s, 1u);
                if (pos < 1024u) list[pos] = kb[2 * i2 + 1];
            }
        }
    } else {
        // fallback: refine to 24-bit threshold (rare: >1024 keys in one bin)
        const unsigned K2 = K - aboveT1_s;
        h[tid] = 0u;
        __syncthreads();
#pragma unroll 4
        for (int i = tid; i < NF; i += 1024) {
            unsigned long long key = kb[i];
            if ((unsigned)(key >> 50) == T1)
                atomicAdd(&h[(unsigned)(key >> 40) & 1023u], 1u);
        }
        __syncthreads();
        unsigned hb = h[tid];
        {
            unsigned tot2;
            unsigned P2 = block_scan_incl(hb, tid, wsum, &tot2);
            unsigned suf = tot2 - P2 + hb;
            unsigned above = tot2 - P2;
            if (above < K2 && K2 <= suf) thr_s = (T1 << 10) | (unsigned)tid;
        }
        __syncthreads();
        const unsigned thr24 = thr_s;
#pragma unroll 4
        for (int i = tid; i < NF; i += 1024) {
            unsigned long long key = kb[i];
            if ((unsigned)(key >> 40) >= thr24) {
                unsigned pos = atomicAdd(&cnt_s, 1u);
                if (pos < 1024u) list[pos] = key;
            }
        }
    }
    __syncthreads();
    const int cc = (int)(cnt_s > 1024u ? 1024u : cnt_s);

    // exhaustive ranking: keys unique -> exact permutation, no barriers
    if (tid < cc) {
        unsigned long long mykey = list[tid];
        unsigned r = 0;
#pragma unroll 8
        for (int j = 0; j < cc; ++j) r += (list[j] > mykey) ? 1u : 0u;
        if (r < (unsigned)NK) {
            int idx = (int)(~(unsigned)(mykey & 0xFFFFFFFFull));
            tki[b * NK + (int)r] = idx;
            int c0 = fcoords[((size_t)b * NF + idx) * 2 + 0];
            int c1 = fcoords[((size_t)b * NF + idx) * 2 + 1];
            size_t o = (size_t)(b * NK + (int)r);
            out1[o * 3 + 0] = (float)b;
            out1[o * 3 + 1] = (float)c0;
            out1[o * 3 + 2] = (float)c1;
            float wx = __fadd_rn(__fmul_rn(__fmul_rn(__fadd_rn((float)c0, 0.5f), 8.0f), 0.075f), -54.0f);
            float wy = __fadd_rn(__fmul_rn(__fmul_rn(__fadd_rn((float)c1, 0.5f), 8.0f), 0.075f), -54.0f);
            keyworld[o * 2 + 0] = wx;
            keyworld[o * 2 + 1] = wy;
            out4[o] = (float)cls[(size_t)b * NF + idx];
        }
    }
}

// ---------------------------------------------------------------------------
// K3: grid-accelerated radius-KNN (unchanged).
// ---------------------------------------------------------------------------
__global__ __launch_bounds__(256) void knn_kernel(
    const float* __restrict__ sfa, const float* __restrict__ sfb,
    const int* __restrict__ gstart,
    const float2* __restrict__ pts, const int* __restrict__ pidx,
    const float* __restrict__ knn_w,
    const float* __restrict__ knn_b,
    const float* __restrict__ keyworld,
    float* __restrict__ mf)
{
    __shared__ unsigned long long list[1024];
    __shared__ float psum[128];
    __shared__ unsigned cnt_s;
    const int tid = threadIdx.x;
    const int blk = blockIdx.x;
    const int s = blk / (BB * NK);
    const int rest = blk % (BB * NK);
    const int b = rest / NK;
    const int r = rest % NK;
    const float* sfeat = s ? sfb : sfa;
    const float r2 = s ? (float)(4.8 * 4.8) : (float)(2.4 * 2.4);
    const float inv_h = s ? (1.0f / HB) : (1.0f / HA);
    const int nc = s ? NCB : NCA;
    const int stb = STB(s, b);
    const size_t pbase = ((size_t)s * BB + b) * NS;

    if (tid == 0) cnt_s = 0u;
    __syncthreads();
    const float kx = keyworld[((size_t)b * NK + r) * 2 + 0];
    const float ky = keyworld[((size_t)b * NK + r) * 2 + 1];
    int cx = (int)floorf((kx + 54.0f) * inv_h);
    int cy = (int)floorf((ky + 54.0f) * inv_h);
    cx = min(max(cx, 0), nc - 1);
    cy = min(max(cy, 0), nc - 1);
    const int c0 = max(cx - 1, 0), c1 = min(cx + 1, nc - 1);
    const int cy0 = max(cy - 1, 0), cy1 = min(cy + 1, nc - 1);

    for (int cyy = cy0; cyy <= cy1; ++cyy) {
        int lo = gstart[stb + cyy * nc + c0];
        int hi = gstart[stb + cyy * nc + c1 + 1];
        for (int p = lo + tid; p < hi; p += 256) {
            float2 w = pts[pbase + p];
            float dx = __fsub_rn(kx, w.x);
            float dy = __fsub_rn(ky, w.y);
            float d2 = __fadd_rn(__fmul_rn(dx, dx), __fmul_rn(dy, dy));
            if (d2 <= r2) {
                unsigned pos = atomicAdd(&cnt_s, 1u);
                if (pos < 1024u)
                    list[pos] = ((unsigned long long)__float_as_uint(d2) << 32)
                              | (unsigned)pidx[pbase + p];
            }
        }
    }
    __syncthreads();
    int cc = (int)cnt_s;
    if (cc > 1024) cc = 1024;
    int n2 = 16;
    while (n2 < cc) n2 <<= 1;
    for (int i = tid; i < n2; i += 256)
        if (i >= cc) list[i] = ~0ull;
    __syncthreads();
    for (int kk = 2; kk <= n2; kk <<= 1) {
        for (int j = kk >> 1; j > 0; j >>= 1) {
            for (int i = tid; i < n2; i += 256) {
                int ixj = i ^ j;
                if (ixj > i) {
                    unsigned long long a = list[i], bv = list[ixj];
                    bool up = ((i & kk) == 0);
                    bool sw = up ? (a > bv) : (a < bv);
                    if (sw) { list[i] = bv; list[ixj] = a; }
                }
            }
            __syncthreads();
        }
    }
    {
        int K = cc < KNN ? cc : KNN;
        int col = tid & 127, half = tid >> 7;
        float acc = 0.f;
        int k0 = half * 8, k1 = min(K, half * 8 + 8);
        for (int k = k0; k < k1; ++k) {
            unsigned i = (unsigned)(list[k] & 0xFFFFFFFFull);
            acc += knn_w[s * 16 + k] * sfeat[((size_t)b * NS + i) * CH + col];
        }
        if (half) psum[col] = acc;
        __syncthreads();
        if (!half)
            mf[(((size_t)s * BB + b) * NK + r) * CH + col] = knn_b[s] + acc + psum[col];
    }
}

// ---------------------------------------------------------------------------
// K4: fuse MLP (unchanged: direct L2-resident float4 weight loads,
// 8-16 in flight, transposed activations, split-K tree reduce).
// ---------------------------------------------------------------------------
__global__ __launch_bounds__(1024) void fuse_kernel(
    const float* __restrict__ ffeat,
    const int* __restrict__ tki,
    const float* __restrict__ kw_w1, const float* __restrict__ kw_g1,
    const float* __restrict__ kw_b1, const float* __restrict__ kw_w2,
    const float* __restrict__ kw_b2,
    const float* __restrict__ fuse_w1, const float* __restrict__ fuse_g1,
    const float* __restrict__ fuse_b1, const float* __restrict__ fuse_w2,
    const float* __restrict__ fuse_b2,
    const float* __restrict__ mf,
    float* __restrict__ out0)
{
    __shared__ float pL[16384];     // 64 KB split-K partials
    __shared__ float xsT[512];      // x transposed [k][key]
    __shared__ float mfs[1024];     // [src][key][c]
    __shared__ float fusedvT[1024]; // [k][key]
    __shared__ float h2sT[1024];    // [k][key]
    __shared__ float prm[964];      // kw_g1|kw_b1|kw_w2|kw_b2|fg1|fb1|fb2
    __shared__ float hsX[256];      // kw hidden [key][k]
    __shared__ float p2[96];
    __shared__ float l3[12];
    __shared__ float wsm[8];
    __shared__ int idxs[KPB], bs[KPB], rs[KPB];
    const int tid = threadIdx.x;
    const int f0 = blockIdx.x * KPB;

    if (tid < 964) {
        float v;
        if (tid < 64)       v = kw_g1[tid];
        else if (tid < 128) v = kw_b1[tid - 64];
        else if (tid < 320) v = kw_w2[tid - 128];
        else if (tid < 323) v = kw_b2[tid - 320];
        else if (tid < 324) v = 0.f;
        else if (tid < 580) v = fuse_g1[tid - 324];
        else if (tid < 836) v = fuse_b1[tid - 580];
        else                v = fuse_b2[tid - 836];
        prm[tid] = v;
    }
    if (tid < KPB) {
        int flat = f0 + tid;
        int b = flat / NK;
        bs[tid] = b;
        rs[tid] = flat - b * NK;
        idxs[tid] = tki[flat];
    }
    __syncthreads();

    if (tid < 128) {
        int key = tid >> 5, c4 = tid & 31;
        float4 v = ((const float4*)(ffeat + ((size_t)bs[key] * NF + idxs[key]) * CH))[c4];
        xsT[(c4 * 4 + 0) * 4 + key] = v.x;
        xsT[(c4 * 4 + 1) * 4 + key] = v.y;
        xsT[(c4 * 4 + 2) * 4 + key] = v.z;
        xsT[(c4 * 4 + 3) * 4 + key] = v.w;
    }
    if (tid < 256) {
        int ss = tid >> 7, key = (tid >> 5) & 3, c4 = tid & 31;
        float4 v = ((const float4*)(mf + (((size_t)ss * BB + bs[key]) * NK + rs[key]) * CH))[c4];
        *(float4*)&mfs[ss * 512 + key * 128 + c4 * 4] = v;
    }
    __syncthreads();

    if (tid < 256) {
        const int og = tid & 15, kseg = tid >> 4;
        float4 wr[8];
#pragma unroll
        for (int m = 0; m < 8; ++m)
            wr[m] = ((const float4*)kw_w1)[(kseg * 8 + m) * 16 + og];
        float4 a0 = {0, 0, 0, 0}, a1 = {0, 0, 0, 0}, a2 = {0, 0, 0, 0}, a3 = {0, 0, 0, 0};
#pragma unroll
        for (int m = 0; m < 8; ++m) {
            float4 f4 = *(const float4*)&xsT[(kseg * 8 + m) * 4];
            fma4(a0, f4.x, wr[m]);
            fma4(a1, f4.y, wr[m]);
            fma4(a2, f4.z, wr[m]);
            fma4(a3, f4.w, wr[m]);
        }
        *(float4*)&pL[(kseg * 4 + 0) * 64 + og * 4] = a0;
        *(float4*)&pL[(kseg * 4 + 1) * 64 + og * 4] = a1;
        *(float4*)&pL[(kseg * 4 + 2) * 64 + og * 4] = a2;
        *(float4*)&pL[(kseg * 4 + 3) * 64 + og * 4] = a3;
    }
    __syncthreads();
    if (tid < 256) {
        int out = tid >> 2, key = tid & 3;
        float s = 0.f;
#pragma unroll
        for (int ks = 0; ks < 16; ++ks) s += pL[(ks * 4 + key) * 64 + out];
        float t = s * prm[out] + prm[64 + out];
        hsX[key * 64 + out] = t > 0.f ? t : 0.f;
    }
    __syncthreads();
    if (tid < 96) {
        int key = tid / 24, rr = tid % 24, out = rr >> 3, seg = rr & 7;
        float acc = 0.f;
#pragma unroll
        for (int m = 0; m < 8; ++m) {
            int k = seg * 8 + m;
            acc += hsX[key * 64 + k] * prm[128 + k * 3 + out];
        }
        p2[(key * 3 + out) * 8 + seg] = acc;
    }
    __syncthreads();
    if (tid < 12) {
        int key = tid / 3, out = tid % 3;
        float s = 0.f;
#pragma unroll
        for (int j = 0; j < 8; ++j) s += p2[(key * 3 + out) * 8 + j];
        l3[key * 3 + out] = s + prm[320 + out];
    }
    __syncthreads();
    if (tid < KPB) {
        float l0 = l3[tid * 3], l1 = l3[tid * 3 + 1], l2 = l3[tid * 3 + 2];
        float m = fmaxf(l0, fmaxf(l1, l2));
        float e0 = expf(l0 - m), e1 = expf(l1 - m), e2 = expf(l2 - m);
        float sum = e0 + e1 + e2;
        wsm[tid * 2 + 0] = e0 / sum;
        wsm[tid * 2 + 1] = e1 / sum;
    }
    __syncthreads();

    {
        int c = tid >> 2, key = tid & 3;
        float w0 = wsm[key * 2], w1_ = wsm[key * 2 + 1];
        float val;
        if (c < 128) {
            float xv_ = xsT[c * 4 + key];
            float m0 = mfs[key * 128 + c];
            float m1 = mfs[512 + key * 128 + c];
            float kv = w0 * xv_;
            float kv2 = w1_ * kv;
            val = kv * m0 + kv2 * m1;
        } else {
            float xv_ = xsT[(c - 128) * 4 + key];
            val = w1_ * (w0 * xv_);
        }
        fusedvT[tid] = val;
    }
    __syncthreads();

    {
        const int og = tid & 63, kseg = tid >> 6;
        const float4* w1v = (const float4*)fuse_w1;
        float4 wr[16];
#pragma unroll
        for (int m = 0; m < 16; ++m)
            wr[m] = w1v[(kseg * 16 + m) * 64 + og];
        float4 a0 = {0, 0, 0, 0}, a1 = {0, 0, 0, 0}, a2 = {0, 0, 0, 0}, a3 = {0, 0, 0, 0};
#pragma unroll
        for (int m = 0; m < 16; ++m) {
            float4 f4 = *(const float4*)&fusedvT[(kseg * 16 + m) * 4];
            fma4(a0, f4.x, wr[m]);
            fma4(a1, f4.y, wr[m]);
            fma4(a2, f4.z, wr[m]);
            fma4(a3, f4.w, wr[m]);
        }
        *(float4*)&pL[(kseg * 4 + 0) * 256 + og * 4] = a0;
        *(float4*)&pL[(kseg * 4 + 1) * 256 + og * 4] = a1;
        *(float4*)&pL[(kseg * 4 + 2) * 256 + og * 4] = a2;
        *(float4*)&pL[(kseg * 4 + 3) * 256 + og * 4] = a3;
    }
    __syncthreads();
    {
        int out = tid >> 2, key = tid & 3;
        float s = 0.f;
#pragma unroll
        for (int ks = 0; ks < 16; ++ks) s += pL[(ks * 4 + key) * 256 + out];
        float t = s * prm[324 + out] + prm[580 + out];
        h2sT[out * 4 + key] = t > 0.f ? t : 0.f;
    }
    __syncthreads();

    {
        const int og2 = tid & 31, kseg2 = tid >> 5;
        const float4* w2v = (const float4*)fuse_w2;
        float4 wr[8];
#pragma unroll
        for (int m = 0; m < 8; ++m)
            wr[m] = w2v[(kseg2 * 8 + m) * 32 + og2];
        float4 a0 = {0, 0, 0, 0}, a1 = {0, 0, 0, 0}, a2 = {0, 0, 0, 0}, a3 = {0, 0, 0, 0};
#pragma unroll
        for (int m = 0; m < 8; ++m) {
            float4 f4 = *(const float4*)&h2sT[(kseg2 * 8 + m) * 4];
            fma4(a0, f4.x, wr[m]);
            fma4(a1, f4.y, wr[m]);
            fma4(a2, f4.z, wr[m]);
            fma4(a3, f4.w, wr[m]);
        }
        *(float4*)&pL[(kseg2 * 4 + 0) * 128 + og2 * 4] = a0;
        *(float4*)&pL[(kseg2 * 4 + 1) * 128 + og2 * 4] = a1;
        *(float4*)&pL[(kseg2 * 4 + 2) * 128 + og2 * 4] = a2;
        *(float4*)&pL[(kseg2 * 4 + 3) * 128 + og2 * 4] = a3;
    }
    __syncthreads();
    if (tid < 512) {
        int out = tid >> 2, key = tid & 3;
        float s = prm[836 + out];
#pragma unroll
        for (int ks = 0; ks < 32; ++ks) s += pL[(ks * 4 + key) * 128 + out];
        out0[((size_t)bs[key] * NK + rs[key]) * CH + out] = s;
    }
}

extern "C" void kernel_launch(void* const* d_in, const int* in_sizes, int n_in,
                              void* d_out, int out_size, void* d_ws, size_t ws_size,
                              hipStream_t stream)
{
    const float* fusion_feat = (const float*)d_in[0];
    const float* src_feat_a  = (const float*)d_in[1];
    const float* src_feat_b  = (const float*)d_in[2];
    const float* heat_w1 = (const float*)d_in[3];
    const float* heat_g1 = (const float*)d_in[4];
    const float* heat_b1 = (const float*)d_in[5];
    const float* heat_w2 = (const float*)d_in[6];
    const float* heat_b2 = (const float*)d_in[7];
    const float* knn_w   = (const float*)d_in[8];
    const float* knn_b   = (const float*)d_in[9];
    const float* kw_w1   = (const float*)d_in[10];
    const float* kw_g1   = (const float*)d_in[11];
    const float* kw_b1   = (const float*)d_in[12];
    const float* kw_w2   = (const float*)d_in[13];
    const float* kw_b2   = (const float*)d_in[14];
    const float* fuse_w1 = (const float*)d_in[15];
    const float* fuse_g1 = (const float*)d_in[16];
    const float* fuse_b1 = (const float*)d_in[17];
    const float* fuse_w2 = (const float*)d_in[18];
    const float* fuse_b2 = (const float*)d_in[19];
    const int* fusion_coords = (const int*)d_in[20];
    const int* src_coords_a  = (const int*)d_in[21];
    const int* src_coords_b  = (const int*)d_in[22];

    float* out = (float*)d_out;
    char* ws = (char*)d_ws;
    int* cls = (int*)(ws + WS_CLS);
    int* tki = (int*)(ws + WS_TKI);
    float* keyworld = (float*)(ws + WS_KW);
    float* mf = (float*)(ws + WS_MF);
    unsigned long long* keys = (unsigned long long*)(ws + WS_KEYS);
    int* bh = (int*)(ws + WS_BH);
    int* gstart = (int*)(ws + WS_GSTART);
    float2* pts = (float2*)(ws + WS_PTS);
    int* pidx = (int*)(ws + WS_PIDX);

    heat_kernel<<<(BB * NF) / 64 + 4 * GB, 256, 0, stream>>>(
        fusion_feat, heat_w1, heat_g1, heat_b1, heat_w2, heat_b2,
        out + OUT2_OFF, out + OUT3_OFF, cls, keys,
        src_coords_a, src_coords_b, bh);

    mid_kernel<<<2 + 4 * GB, 1024, 0, stream>>>(
        keys, cls, fusion_coords,
        out + OUT1_OFF, out + OUT4_OFF, tki, keyworld,
        src_coords_a, src_coords_b, bh, gstart, pts, pidx);

    knn_kernel<<<2 * BB * NK, 256, 0, stream>>>(
        src_feat_a, src_feat_b, gstart, pts, pidx,
        knn_w, knn_b, keyworld, mf);

    fuse_kernel<<<(BB * NK) / KPB, 1024, 0, stream>>>(
        fusion_feat, tki, kw_w1, kw_g1, kw_b1, kw_w2, kw_b2,
        fuse_w1, fuse_g1, fuse_b1, fuse_w2, fuse_b2, mf, out + OUT0_OFF);
}

// Round 7
// 216.022 us; speedup vs baseline: 1.5187x; 1.0630x over previous
//
#include <hip/hip_runtime.h>
#include <math.h>

#define BB 2
#define NF 20000
#define NS 30000
#define CH 128
#define NK 500
#define KNN 16
#define KPB 4

// grid params: cell = 1.001 * radius (margin vs float boundary rounding)
#define HA 2.4024f
#define HB 4.8048f
#define NCA 45
#define NCB 23
#define CELLS_A 2025
#define CELLS_B 529

// multi-block counting sort for the spatial grid
#define GB 8                 // count/scatter blocks per (s,b)
#define SLICE 3750           // NS / GB points per block
#define SLICE4 1875          // int4 (2-point) loads per slice

// output offsets (floats, concatenated in return order)
#define OUT0_OFF 0           // out          (B*NK*128) = 128000
#define OUT1_OFF 128000      // key_voxel_indices (B*NK*3) = 3000
#define OUT2_OFF 131000      // heat_scores  (B*NF) = 40000
#define OUT3_OFF 171000      // scores10     (B*NF*10) = 400000
#define OUT4_OFF 571000      // key_class    (B*NK) = 1000

// workspace offsets (bytes)
#define WS_CLS   0           // int32  x 40000
#define WS_TKI   160000      // int32  x 1000
#define WS_KW    164000      // float  x 2000
#define WS_MF    172000      // float  x 256000 (1,024,000 B)
#define WS_KEYS  WS_MF       // u64 x 40000 overlays mf head (temporally disjoint)
#define WS_BH    492000      // int x 65536: per-block hists [sb][g][2048], overlays mf
#define WS_RAWK  754144      // u32 x 40000: ordf(raw logit) for topk binning, overlays mf
#define WS_GSTART 1196000    // int x 5112 (cell starts, +1 per (s,b))
#define WS_PTS    1236880    // float2 x 120000 (sorted world coords)
#define WS_PIDX   2196880    // int x 120000 (sorted original indices)

#define STB(s,b)  ((s) ? (4052 + (b) * 530) : ((b) * 2026))

__device__ __forceinline__ void fma4(float4& acc, float sc, const float4& wv) {
    acc.x += sc * wv.x; acc.y += sc * wv.y;
    acc.z += sc * wv.z; acc.w += sc * wv.w;
}

__device__ __forceinline__ unsigned ordf(float s) {
    unsigned u = __float_as_uint(s);
    return (u & 0x80000000u) ? ~u : (u | 0x80000000u);
}

// identical arithmetic in count and scatter phases (bitwise-consistent cells)
__device__ __forceinline__ int cell_of(int cxi, int cyi, float stride, float inv_h,
                                       int nc, float& sx, float& sy)
{
    sx = __fadd_rn(__fmul_rn(__fmul_rn(__fadd_rn((float)cxi, 0.5f), stride), 0.075f), -54.0f);
    sy = __fadd_rn(__fmul_rn(__fmul_rn(__fadd_rn((float)cyi, 0.5f), stride), 0.075f), -54.0f);
    int cx = (int)floorf((sx + 54.0f) * inv_h);
    int cy = (int)floorf((sy + 54.0f) * inv_h);
    cx = min(max(cx, 0), nc - 1);
    cy = min(max(cy, 0), nc - 1);
    return cy * nc + cx;
}

// 1024-thread inclusive scan: wave shfl scan + 16 wave-sum exchange.
__device__ __forceinline__ unsigned block_scan_incl(unsigned v, int tid,
                                                    volatile unsigned* ws,
                                                    unsigned* total)
{
    const int lane = tid & 63, wid = tid >> 6;
    unsigned p = v;
#pragma unroll
    for (int off = 1; off < 64; off <<= 1) {
        unsigned t = (unsigned)__shfl_up((int)p, off);
        if (lane >= off) p += t;
    }
    __syncthreads();
    if (lane == 63) ws[wid] = p;
    __syncthreads();
    unsigned woff = 0, tot = 0;
#pragma unroll
    for (int w = 0; w < 16; ++w) {
        unsigned s = ws[w];
        tot += s;
        if (w < wid) woff += s;
    }
    *total = tot;
    return p + woff;
}

// ---------------------------------------------------------------------------
// K1: blocks 0-31 = grid COUNT phase; blocks 32+ = heat MLP SGEMM (K-chunk 32,
// unioned LDS pool -> 4 blocks/CU). Epilogue now also writes rawk = ordf(raw
// logit): sigmoid compresses all keys into ~17 of 16384 histogram bins (fixed
// exponent), which forced mid's topk onto its 3-pass fallback every run and
// serialized its LDS atomics ~1150-deep. Raw-logit bins spread ~190 wide.
// Final ranking keys stay sigmoid-based -> output bit-identical.
// ---------------------------------------------------------------------------
__global__ __launch_bounds__(256) void heat_kernel(
    const float* __restrict__ x,
    const float* __restrict__ w1,
    const float* __restrict__ g1, const float* __restrict__ b1,
    const float* __restrict__ w2,
    const float* __restrict__ b2,
    float* __restrict__ out_heat,
    float* __restrict__ out_s10,
    int* __restrict__ cls,
    unsigned long long* __restrict__ keys,
    const int* __restrict__ sca, const int* __restrict__ scb,
    int* __restrict__ bh,
    unsigned* __restrict__ rawk)
{
    __shared__ float Pool[8448];    // GEMM: As=[0,2304) s36, Ws=[2304,6528) s132 ; Epi: Hs s132
    __shared__ float W2s[1280];
    const int tid = threadIdx.x;

    if (blockIdx.x < 4 * GB) {
        const int gflat = blockIdx.x;
        const int sb = gflat >> 3;          // 0..3
        const int gg = gflat & (GB - 1);    // 0..7
        const int s = sb >> 1, b = sb & 1;
        const float stride = s ? 8.0f : 4.0f;
        const float inv_h = s ? (1.0f / HB) : (1.0f / HA);
        const int nc = s ? NCB : NCA;
        const int2* sc = ((const int2*)(s ? scb : sca)) + (size_t)b * NS;
        const int4* scv = (const int4*)sc;
        int* hist_l = (int*)Pool;           // 2048 ints

        for (int i = tid; i < 2048; i += 256) hist_l[i] = 0;
        __syncthreads();
        for (int p = gg * SLICE4 + tid; p < (gg + 1) * SLICE4; p += 256) {
            int4 v = scv[p];
            float sx, sy;
            int cell0 = cell_of(v.x, v.y, stride, inv_h, nc, sx, sy);
            int cell1 = cell_of(v.z, v.w, stride, inv_h, nc, sx, sy);
            atomicAdd(&hist_l[cell0], 1);
            atomicAdd(&hist_l[cell1], 1);
        }
        __syncthreads();
        int* bhp = bh + (gflat << 11);
        for (int i = tid; i < 2048; i += 256) bhp[i] = hist_l[i];
        return;
    }

    const int m0 = (blockIdx.x - 4 * GB) * 64;
    const int tx = tid & 15;
    const int ty = tid >> 4;
    float* As = Pool;               // 64 rows, stride 36
    float* Ws = Pool + 2304;        // 32 rows, stride 132

    for (int v = tid; v < 1280; v += 256) W2s[v] = w2[v];

    float acc[4][8];
#pragma unroll
    for (int i = 0; i < 4; ++i)
#pragma unroll
        for (int j = 0; j < 8; ++j) acc[i][j] = 0.f;

    const float4* xv = (const float4*)x;
    const float4* w1v = (const float4*)w1;

    for (int kc = 0; kc < 128; kc += 32) {
#pragma unroll
        for (int i = 0; i < 2; ++i) {
            int v = tid + i * 256;
            int row = v >> 3, c4 = v & 7;
            float4 val = xv[(size_t)(m0 + row) * 32 + (kc >> 2) + c4];
            *(float4*)&As[row * 36 + c4 * 4] = val;
        }
#pragma unroll
        for (int i = 0; i < 4; ++i) {
            int v = tid + i * 256;
            int k = v >> 5, c4 = v & 31;
            float4 val = w1v[(size_t)(kc + k) * 32 + c4];
            *(float4*)&Ws[k * 132 + c4 * 4] = val;
        }
        __syncthreads();

        const float* a0p = &As[(ty * 4 + 0) * 36];
        const float* a1p = &As[(ty * 4 + 1) * 36];
        const float* a2p = &As[(ty * 4 + 2) * 36];
        const float* a3p = &As[(ty * 4 + 3) * 36];
#pragma unroll 4
        for (int k = 0; k < 32; ++k) {
            float4 bA = *(const float4*)&Ws[k * 132 + tx * 4];
            float4 bB = *(const float4*)&Ws[k * 132 + 64 + tx * 4];
            float a0 = a0p[k], a1 = a1p[k], a2 = a2p[k], a3 = a3p[k];
            acc[0][0] += a0 * bA.x; acc[0][1] += a0 * bA.y; acc[0][2] += a0 * bA.z; acc[0][3] += a0 * bA.w;
            acc[0][4] += a0 * bB.x; acc[0][5] += a0 * bB.y; acc[0][6] += a0 * bB.z; acc[0][7] += a0 * bB.w;
            acc[1][0] += a1 * bA.x; acc[1][1] += a1 * bA.y; acc[1][2] += a1 * bA.z; acc[1][3] += a1 * bA.w;
            acc[1][4] += a1 * bB.x; acc[1][5] += a1 * bB.y; acc[1][6] += a1 * bB.z; acc[1][7] += a1 * bB.w;
            acc[2][0] += a2 * bA.x; acc[2][1] += a2 * bA.y; acc[2][2] += a2 * bA.z; acc[2][3] += a2 * bA.w;
            acc[2][4] += a2 * bB.x; acc[2][5] += a2 * bB.y; acc[2][6] += a2 * bB.z; acc[2][7] += a2 * bB.w;
            acc[3][0] += a3 * bA.x; acc[3][1] += a3 * bA.y; acc[3][2] += a3 * bA.z; acc[3][3] += a3 * bA.w;
            acc[3][4] += a3 * bB.x; acc[3][5] += a3 * bB.y; acc[3][6] += a3 * bB.z; acc[3][7] += a3 * bB.w;
        }
        __syncthreads();
    }

    float4 g1a = ((const float4*)g1)[tx], g1b = ((const float4*)g1)[16 + tx];
    float4 b1a = ((const float4*)b1)[tx], b1b = ((const float4*)b1)[16 + tx];
    float* Hs = Pool;               // 64 rows, stride 132 (reuses As+Ws space)
#pragma unroll
    for (int i = 0; i < 4; ++i) {
        int row = ty * 4 + i;
        float4 hA, hB;
        hA.x = fmaxf(acc[i][0] * g1a.x + b1a.x, 0.f);
        hA.y = fmaxf(acc[i][1] * g1a.y + b1a.y, 0.f);
        hA.z = fmaxf(acc[i][2] * g1a.z + b1a.z, 0.f);
        hA.w = fmaxf(acc[i][3] * g1a.w + b1a.w, 0.f);
        hB.x = fmaxf(acc[i][4] * g1b.x + b1b.x, 0.f);
        hB.y = fmaxf(acc[i][5] * g1b.y + b1b.y, 0.f);
        hB.z = fmaxf(acc[i][6] * g1b.z + b1b.z, 0.f);
        hB.w = fmaxf(acc[i][7] * g1b.w + b1b.w, 0.f);
        *(float4*)&Hs[row * 132 + tx * 4] = hA;
        *(float4*)&Hs[row * 132 + 64 + tx * 4] = hB;
    }
    __syncthreads();

    const int r = tid >> 2;
    const int p = tid & 3;
    float a2[10];
#pragma unroll
    for (int c = 0; c < 10; ++c) a2[c] = 0.f;
    for (int kk = 0; kk < 32; ++kk) {
        int k = kk * 4 + p;
        float hv = Hs[r * 132 + k];
#pragma unroll
        for (int c = 0; c < 10; ++c) a2[c] += hv * W2s[k * 10 + c];
    }
#pragma unroll
    for (int c = 0; c < 10; ++c) {
        a2[c] += __shfl_xor(a2[c], 1);
        a2[c] += __shfl_xor(a2[c], 2);
    }
    if (p == 0) {
        int m = m0 + r;
        float best = -INFINITY;
        int bi = 0;
#pragma unroll
        for (int c = 0; c < 10; ++c) {
            float s = a2[c] + b2[c];
            out_s10[(size_t)m * 10 + c] = s;
            if (s > best) { best = s; bi = c; }
        }
        out_heat[m] = best;
        cls[m] = bi;
        int b = m / NF;
        unsigned i = (unsigned)(m - b * NF);
        float sig = 1.0f / (1.0f + expf(-best));
        keys[m] = ((unsigned long long)ordf(sig) << 32) | (unsigned)(~i);
        rawk[m] = ordf(best);
    }
}

// ---------------------------------------------------------------------------
// K2: blocks 0-1 = topk — selection histogram now bins on rawk (raw-logit
// ordf, ~190 live bins) instead of the sigmoid key (~17 live bins): kills the
// always-on 3-pass fallback and the ~1150-deep same-address LDS atomic
// chains. Candidate set is monotonically consistent with the sigmoid keys;
// ranking still uses the sigmoid keys -> bit-identical output.
// Blocks 2-33 = grid SCAN+SCATTER (unchanged).
// ---------------------------------------------------------------------------
#define H1BINS 16384

__global__ __launch_bounds__(1024) void mid_kernel(
    const unsigned long long* __restrict__ keys,
    const unsigned* __restrict__ rawk,
    const int* __restrict__ cls,
    const int* __restrict__ fcoords,
    float* __restrict__ out1,
    float* __restrict__ out4,
    int* __restrict__ tki,
    float* __restrict__ keyworld,
    const int* __restrict__ sca, const int* __restrict__ scb,
    const int* __restrict__ bh,
    int* __restrict__ gstart,
    float2* __restrict__ pts, int* __restrict__ pidx)
{
    __shared__ unsigned h[H1BINS];            // 64 KB
    __shared__ unsigned long long list[1024]; // 8 KB
    __shared__ unsigned short bins16[NF];     // 40 KB cached raw bin ids
    __shared__ unsigned wsum[16];             // wave-sum exchange for scans
    __shared__ unsigned chunk_s, aboveC_s, T1_s, aboveT1_s, cand_s, thr_s, cnt_s;
    const int tid = threadIdx.x;
    const int blk = blockIdx.x;

    if (blk >= 2) {
        // ---- grid scan + scatter for slice (sb, j) ----
        const int idx = blk - 2;            // 0..31
        const int sb = idx >> 3;            // 0..3
        const int j = idx & (GB - 1);       // 0..7
        const int s = sb >> 1, b = sb & 1;
        const int n = s ? CELLS_B : CELLS_A;
        const int nc = s ? NCB : NCA;
        const float stride = s ? 8.0f : 4.0f;
        const float inv_h = s ? (1.0f / HB) : (1.0f / HA);
        const int stb = STB(s, b);
        const int2* sc = ((const int2*)(s ? scb : sca)) + (size_t)b * NS;
        const int4* scv = (const int4*)sc;
        const size_t pbase = ((size_t)s * BB + b) * NS;
        const int* bhsb = bh + (sb << 14);  // sb * GB * 2048
        int* tot = (int*)h;                 // [0..2047]
        int* cur = ((int*)h) + 2048;        // pre, then cursor  [2048..4095]

        for (int c = tid; c < 2048; c += 1024) {
            int t = 0, pr = 0;
#pragma unroll
            for (int g = 0; g < GB; ++g) {
                int v = bhsb[(g << 11) + c];
                t += v;
                if (g < j) pr += v;
            }
            tot[c] = t;
            cur[c] = pr;                    // pre-sum for this block's cursor
        }
        __syncthreads();
        const int i0 = tid * 2, i1 = tid * 2 + 1;
        int c0 = (i0 < n) ? tot[i0] : 0;
        int c1 = (i1 < n) ? tot[i1] : 0;
        unsigned totsum;
        unsigned P = block_scan_incl((unsigned)(c0 + c1), tid, wsum, &totsum);
        const int excl = (int)P - (c0 + c1);
        if (i0 < n) {
            if (j == 0) gstart[stb + i0] = excl;
            cur[i0] += excl;
        }
        if (i1 < n) {
            if (j == 0) gstart[stb + i1] = excl + c0;
            cur[i1] += excl + c0;
        }
        if (j == 0 && tid == 0) gstart[stb + n] = NS;
        __syncthreads();
        for (int p = j * SLICE4 + tid; p < (j + 1) * SLICE4; p += 1024) {
            int4 v = scv[p];
            float sx0, sy0, sx1, sy1;
            int cell0 = cell_of(v.x, v.y, stride, inv_h, nc, sx0, sy0);
            int cell1 = cell_of(v.z, v.w, stride, inv_h, nc, sx1, sy1);
            int pos0 = atomicAdd(&cur[cell0], 1);
            int pos1 = atomicAdd(&cur[cell1], 1);
            pts[pbase + pos0] = make_float2(sx0, sy0);
            pidx[pbase + pos0] = p * 2;
            pts[pbase + pos1] = make_float2(sx1, sy1);
            pidx[pbase + pos1] = p * 2 + 1;
        }
        return;
    }

    // ---- topk for batch b = blk ----
    const int b = blk;
    const unsigned long long* kb = keys + (size_t)b * NF;
    const unsigned* rk = rawk + (size_t)b * NF;
    const unsigned K = NK;

    for (int i = tid; i < H1BINS; i += 1024) h[i] = 0u;
    __syncthreads();
    // paired raw-bin loads; cache 14-bit raw bins in LDS; plain LDS atomics
    for (int i2 = tid; i2 < NF / 2; i2 += 1024) {
        uint2 rv = ((const uint2*)rk)[i2];
        unsigned b0 = rv.x >> 18;
        unsigned b1_ = rv.y >> 18;
        bins16[2 * i2] = (unsigned short)b0;
        bins16[2 * i2 + 1] = (unsigned short)b1_;
        atomicAdd(&h[b0], 1u);
        atomicAdd(&h[b1_], 1u);
    }
    __syncthreads();
    unsigned ck = 0;
    {
        int base = tid * 16;
#pragma unroll
        for (int j = 0; j < 16; ++j) ck += h[base + j];
    }
    {
        unsigned tot;
        unsigned P = block_scan_incl(ck, tid, wsum, &tot);
        unsigned suf = tot - P + ck;     // inclusive suffix
        unsigned above = tot - P;        // exclusive suffix
        if (above < K && K <= suf) { chunk_s = (unsigned)tid; aboveC_s = above; }
    }
    __syncthreads();
    if (tid == 0) {
        int bin = (int)chunk_s * 16 + 15;
        unsigned acc = aboveC_s;
        for (;; --bin) { if (acc + h[bin] >= K) break; acc += h[bin]; }
        T1_s = (unsigned)bin;
        aboveT1_s = acc;
        cand_s = acc + h[bin];
        cnt_s = 0u;
    }
    __syncthreads();
    const unsigned T1 = T1_s;

    if (cand_s <= 1024u) {
        // collect via cached LDS raw bins (u32 = 2 bins per read); gather only
        // candidate sigmoid keys (<=1024 total) from global
        const unsigned* b32v = (const unsigned*)bins16;
        for (int i2 = tid; i2 < NF / 2; i2 += 1024) {
            unsigned pk = b32v[i2];
            if ((pk & 0xFFFFu) >= T1) {
                unsigned pos = atomicAdd(&cnt_s, 1u);
                if (pos < 1024u) list[pos] = kb[2 * i2];
            }
            if ((pk >> 16) >= T1) {
                unsigned pos = atomicAdd(&cnt_s, 1u);
                if (pos < 1024u) list[pos] = kb[2 * i2 + 1];
            }
        }
    } else {
        // rare fallback: refine within raw bin T1 on bits 17..8 of rawk
        const unsigned K2 = K - aboveT1_s;
        h[tid] = 0u;
        __syncthreads();
#pragma unroll 4
        for (int i = tid; i < NF; i += 1024) {
            unsigned rw = rk[i];
            if ((rw >> 18) == T1)
                atomicAdd(&h[(rw >> 8) & 1023u], 1u);
        }
        __syncthreads();
        unsigned hb = h[tid];
        {
            unsigned tot2;
            unsigned P2 = block_scan_incl(hb, tid, wsum, &tot2);
            unsigned suf = tot2 - P2 + hb;
            unsigned above = tot2 - P2;
            if (above < K2 && K2 <= suf) thr_s = (T1 << 10) | (unsigned)tid;
        }
        __syncthreads();
        const unsigned thr24 = thr_s;
#pragma unroll 4
        for (int i = tid; i < NF; i += 1024) {
            unsigned rw = rk[i];
            if ((rw >> 8) >= thr24) {
                unsigned pos = atomicAdd(&cnt_s, 1u);
                if (pos < 1024u) list[pos] = kb[i];
            }
        }
    }
    __syncthreads();
    const int cc = (int)(cnt_s > 1024u ? 1024u : cnt_s);

    // exhaustive ranking on sigmoid keys: unique -> exact permutation
    if (tid < cc) {
        unsigned long long mykey = list[tid];
        unsigned r = 0;
#pragma unroll 8
        for (int j = 0; j < cc; ++j) r += (list[j] > mykey) ? 1u : 0u;
        if (r < (unsigned)NK) {
            int idx = (int)(~(unsigned)(mykey & 0xFFFFFFFFull));
            tki[b * NK + (int)r] = idx;
            int c0 = fcoords[((size_t)b * NF + idx) * 2 + 0];
            int c1 = fcoords[((size_t)b * NF + idx) * 2 + 1];
            size_t o = (size_t)(b * NK + (int)r);
            out1[o * 3 + 0] = (float)b;
            out1[o * 3 + 1] = (float)c0;
            out1[o * 3 + 2] = (float)c1;
            float wx = __fadd_rn(__fmul_rn(__fmul_rn(__fadd_rn((float)c0, 0.5f), 8.0f), 0.075f), -54.0f);
            float wy = __fadd_rn(__fmul_rn(__fmul_rn(__fadd_rn((float)c1, 0.5f), 8.0f), 0.075f), -54.0f);
            keyworld[o * 2 + 0] = wx;
            keyworld[o * 2 + 1] = wy;
            out4[o] = (float)cls[(size_t)b * NF + idx];
        }
    }
}

// ---------------------------------------------------------------------------
// K3: grid-accelerated radius-KNN (unchanged).
// ---------------------------------------------------------------------------
__global__ __launch_bounds__(256) void knn_kernel(
    const float* __restrict__ sfa, const float* __restrict__ sfb,
    const int* __restrict__ gstart,
    const float2* __restrict__ pts, const int* __restrict__ pidx,
    const float* __restrict__ knn_w,
    const float* __restrict__ knn_b,
    const float* __restrict__ keyworld,
    float* __restrict__ mf)
{
    __shared__ unsigned long long list[1024];
    __shared__ float psum[128];
    __shared__ unsigned cnt_s;
    const int tid = threadIdx.x;
    const int blk = blockIdx.x;
    const int s = blk / (BB * NK);
    const int rest = blk % (BB * NK);
    const int b = rest / NK;
    const int r = rest % NK;
    const float* sfeat = s ? sfb : sfa;
    const float r2 = s ? (float)(4.8 * 4.8) : (float)(2.4 * 2.4);
    const float inv_h = s ? (1.0f / HB) : (1.0f / HA);
    const int nc = s ? NCB : NCA;
    const int stb = STB(s, b);
    const size_t pbase = ((size_t)s * BB + b) * NS;

    if (tid == 0) cnt_s = 0u;
    __syncthreads();
    const float kx = keyworld[((size_t)b * NK + r) * 2 + 0];
    const float ky = keyworld[((size_t)b * NK + r) * 2 + 1];
    int cx = (int)floorf((kx + 54.0f) * inv_h);
    int cy = (int)floorf((ky + 54.0f) * inv_h);
    cx = min(max(cx, 0), nc - 1);
    cy = min(max(cy, 0), nc - 1);
    const int c0 = max(cx - 1, 0), c1 = min(cx + 1, nc - 1);
    const int cy0 = max(cy - 1, 0), cy1 = min(cy + 1, nc - 1);

    for (int cyy = cy0; cyy <= cy1; ++cyy) {
        int lo = gstart[stb + cyy * nc + c0];
        int hi = gstart[stb + cyy * nc + c1 + 1];
        for (int p = lo + tid; p < hi; p += 256) {
            float2 w = pts[pbase + p];
            float dx = __fsub_rn(kx, w.x);
            float dy = __fsub_rn(ky, w.y);
            float d2 = __fadd_rn(__fmul_rn(dx, dx), __fmul_rn(dy, dy));
            if (d2 <= r2) {
                unsigned pos = atomicAdd(&cnt_s, 1u);
                if (pos < 1024u)
                    list[pos] = ((unsigned long long)__float_as_uint(d2) << 32)
                              | (unsigned)pidx[pbase + p];
            }
        }
    }
    __syncthreads();
    int cc = (int)cnt_s;
    if (cc > 1024) cc = 1024;
    int n2 = 16;
    while (n2 < cc) n2 <<= 1;
    for (int i = tid; i < n2; i += 256)
        if (i >= cc) list[i] = ~0ull;
    __syncthreads();
    for (int kk = 2; kk <= n2; kk <<= 1) {
        for (int j = kk >> 1; j > 0; j >>= 1) {
            for (int i = tid; i < n2; i += 256) {
                int ixj = i ^ j;
                if (ixj > i) {
                    unsigned long long a = list[i], bv = list[ixj];
                    bool up = ((i & kk) == 0);
                    bool sw = up ? (a > bv) : (a < bv);
                    if (sw) { list[i] = bv; list[ixj] = a; }
                }
            }
            __syncthreads();
        }
    }
    {
        int K = cc < KNN ? cc : KNN;
        int col = tid & 127, half = tid >> 7;
        float acc = 0.f;
        int k0 = half * 8, k1 = min(K, half * 8 + 8);
        for (int k = k0; k < k1; ++k) {
            unsigned i = (unsigned)(list[k] & 0xFFFFFFFFull);
            acc += knn_w[s * 16 + k] * sfeat[((size_t)b * NS + i) * CH + col];
        }
        if (half) psum[col] = acc;
        __syncthreads();
        if (!half)
            mf[(((size_t)s * BB + b) * NK + r) * CH + col] = knn_b[s] + acc + psum[col];
    }
}

// ---------------------------------------------------------------------------
// K4: fuse MLP (unchanged: direct L2-resident float4 weight loads,
// 8-16 in flight, transposed activations, split-K tree reduce).
// ---------------------------------------------------------------------------
__global__ __launch_bounds__(1024) void fuse_kernel(
    const float* __restrict__ ffeat,
    const int* __restrict__ tki,
    const float* __restrict__ kw_w1, const float* __restrict__ kw_g1,
    const float* __restrict__ kw_b1, const float* __restrict__ kw_w2,
    const float* __restrict__ kw_b2,
    const float* __restrict__ fuse_w1, const float* __restrict__ fuse_g1,
    const float* __restrict__ fuse_b1, const float* __restrict__ fuse_w2,
    const float* __restrict__ fuse_b2,
    const float* __restrict__ mf,
    float* __restrict__ out0)
{
    __shared__ float pL[16384];     // 64 KB split-K partials
    __shared__ float xsT[512];      // x transposed [k][key]
    __shared__ float mfs[1024];     // [src][key][c]
    __shared__ float fusedvT[1024]; // [k][key]
    __shared__ float h2sT[1024];    // [k][key]
    __shared__ float prm[964];      // kw_g1|kw_b1|kw_w2|kw_b2|fg1|fb1|fb2
    __shared__ float hsX[256];      // kw hidden [key][k]
    __shared__ float p2[96];
    __shared__ float l3[12];
    __shared__ float wsm[8];
    __shared__ int idxs[KPB], bs[KPB], rs[KPB];
    const int tid = threadIdx.x;
    const int f0 = blockIdx.x * KPB;

    if (tid < 964) {
        float v;
        if (tid < 64)       v = kw_g1[tid];
        else if (tid < 128) v = kw_b1[tid - 64];
        else if (tid < 320) v = kw_w2[tid - 128];
        else if (tid < 323) v = kw_b2[tid - 320];
        else if (tid < 324) v = 0.f;
        else if (tid < 580) v = fuse_g1[tid - 324];
        else if (tid < 836) v = fuse_b1[tid - 580];
        else                v = fuse_b2[tid - 836];
        prm[tid] = v;
    }
    if (tid < KPB) {
        int flat = f0 + tid;
        int b = flat / NK;
        bs[tid] = b;
        rs[tid] = flat - b * NK;
        idxs[tid] = tki[flat];
    }
    __syncthreads();

    if (tid < 128) {
        int key = tid >> 5, c4 = tid & 31;
        float4 v = ((const float4*)(ffeat + ((size_t)bs[key] * NF + idxs[key]) * CH))[c4];
        xsT[(c4 * 4 + 0) * 4 + key] = v.x;
        xsT[(c4 * 4 + 1) * 4 + key] = v.y;
        xsT[(c4 * 4 + 2) * 4 + key] = v.z;
        xsT[(c4 * 4 + 3) * 4 + key] = v.w;
    }
    if (tid < 256) {
        int ss = tid >> 7, key = (tid >> 5) & 3, c4 = tid & 31;
        float4 v = ((const float4*)(mf + (((size_t)ss * BB + bs[key]) * NK + rs[key]) * CH))[c4];
        *(float4*)&mfs[ss * 512 + key * 128 + c4 * 4] = v;
    }
    __syncthreads();

    if (tid < 256) {
        const int og = tid & 15, kseg = tid >> 4;
        float4 wr[8];
#pragma unroll
        for (int m = 0; m < 8; ++m)
            wr[m] = ((const float4*)kw_w1)[(kseg * 8 + m) * 16 + og];
        float4 a0 = {0, 0, 0, 0}, a1 = {0, 0, 0, 0}, a2 = {0, 0, 0, 0}, a3 = {0, 0, 0, 0};
#pragma unroll
        for (int m = 0; m < 8; ++m) {
            float4 f4 = *(const float4*)&xsT[(kseg * 8 + m) * 4];
            fma4(a0, f4.x, wr[m]);
            fma4(a1, f4.y, wr[m]);
            fma4(a2, f4.z, wr[m]);
            fma4(a3, f4.w, wr[m]);
        }
        *(float4*)&pL[(kseg * 4 + 0) * 64 + og * 4] = a0;
        *(float4*)&pL[(kseg * 4 + 1) * 64 + og * 4] = a1;
        *(float4*)&pL[(kseg * 4 + 2) * 64 + og * 4] = a2;
        *(float4*)&pL[(kseg * 4 + 3) * 64 + og * 4] = a3;
    }
    __syncthreads();
    if (tid < 256) {
        int out = tid >> 2, key = tid & 3;
        float s = 0.f;
#pragma unroll
        for (int ks = 0; ks < 16; ++ks) s += pL[(ks * 4 + key) * 64 + out];
        float t = s * prm[out] + prm[64 + out];
        hsX[key * 64 + out] = t > 0.f ? t : 0.f;
    }
    __syncthreads();
    if (tid < 96) {
        int key = tid / 24, rr = tid % 24, out = rr >> 3, seg = rr & 7;
        float acc = 0.f;
#pragma unroll
        for (int m = 0; m < 8; ++m) {
            int k = seg * 8 + m;
            acc += hsX[key * 64 + k] * prm[128 + k * 3 + out];
        }
        p2[(key * 3 + out) * 8 + seg] = acc;
    }
    __syncthreads();
    if (tid < 12) {
        int key = tid / 3, out = tid % 3;
        float s = 0.f;
#pragma unroll
        for (int j = 0; j < 8; ++j) s += p2[(key * 3 + out) * 8 + j];
        l3[key * 3 + out] = s + prm[320 + out];
    }
    __syncthreads();
    if (tid < KPB) {
        float l0 = l3[tid * 3], l1 = l3[tid * 3 + 1], l2 = l3[tid * 3 + 2];
        float m = fmaxf(l0, fmaxf(l1, l2));
        float e0 = expf(l0 - m), e1 = expf(l1 - m), e2 = expf(l2 - m);
        float sum = e0 + e1 + e2;
        wsm[tid * 2 + 0] = e0 / sum;
        wsm[tid * 2 + 1] = e1 / sum;
    }
    __syncthreads();

    {
        int c = tid >> 2, key = tid & 3;
        float w0 = wsm[key * 2], w1_ = wsm[key * 2 + 1];
        float val;
        if (c < 128) {
            float xv_ = xsT[c * 4 + key];
            float m0 = mfs[key * 128 + c];
            float m1 = mfs[512 + key * 128 + c];
            float kv = w0 * xv_;
            float kv2 = w1_ * kv;
            val = kv * m0 + kv2 * m1;
        } else {
            float xv_ = xsT[(c - 128) * 4 + key];
            val = w1_ * (w0 * xv_);
        }
        fusedvT[tid] = val;
    }
    __syncthreads();

    {
        const int og = tid & 63, kseg = tid >> 6;
        const float4* w1v = (const float4*)fuse_w1;
        float4 wr[16];
#pragma unroll
        for (int m = 0; m < 16; ++m)
            wr[m] = w1v[(kseg * 16 + m) * 64 + og];
        float4 a0 = {0, 0, 0, 0}, a1 = {0, 0, 0, 0}, a2 = {0, 0, 0, 0}, a3 = {0, 0, 0, 0};
#pragma unroll
        for (int m = 0; m < 16; ++m) {
            float4 f4 = *(const float4*)&fusedvT[(kseg * 16 + m) * 4];
            fma4(a0, f4.x, wr[m]);
            fma4(a1, f4.y, wr[m]);
            fma4(a2, f4.z, wr[m]);
            fma4(a3, f4.w, wr[m]);
        }
        *(float4*)&pL[(kseg * 4 + 0) * 256 + og * 4] = a0;
        *(float4*)&pL[(kseg * 4 + 1) * 256 + og * 4] = a1;
        *(float4*)&pL[(kseg * 4 + 2) * 256 + og * 4] = a2;
        *(float4*)&pL[(kseg * 4 + 3) * 256 + og * 4] = a3;
    }
    __syncthreads();
    {
        int out = tid >> 2, key = tid & 3;
        float s = 0.f;
#pragma unroll
        for (int ks = 0; ks < 16; ++ks) s += pL[(ks * 4 + key) * 256 + out];
        float t = s * prm[324 + out] + prm[580 + out];
        h2sT[out * 4 + key] = t > 0.f ? t : 0.f;
    }
    __syncthreads();

    {
        const int og2 = tid & 31, kseg2 = tid >> 5;
        const float4* w2v = (const float4*)fuse_w2;
        float4 wr[8];
#pragma unroll
        for (int m = 0; m < 8; ++m)
            wr[m] = w2v[(kseg2 * 8 + m) * 32 + og2];
        float4 a0 = {0, 0, 0, 0}, a1 = {0, 0, 0, 0}, a2 = {0, 0, 0, 0}, a3 = {0, 0, 0, 0};
#pragma unroll
        for (int m = 0; m < 8; ++m) {
            float4 f4 = *(const float4*)&h2sT[(kseg2 * 8 + m) * 4];
            fma4(a0, f4.x, wr[m]);
            fma4(a1, f4.y, wr[m]);
            fma4(a2, f4.z, wr[m]);
            fma4(a3, f4.w, wr[m]);
        }
        *(float4*)&pL[(kseg2 * 4 + 0) * 128 + og2 * 4] = a0;
        *(float4*)&pL[(kseg2 * 4 + 1) * 128 + og2 * 4] = a1;
        *(float4*)&pL[(kseg2 * 4 + 2) * 128 + og2 * 4] = a2;
        *(float4*)&pL[(kseg2 * 4 + 3) * 128 + og2 * 4] = a3;
    }
    __syncthreads();
    if (tid < 512) {
        int out = tid >> 2, key = tid & 3;
        float s = prm[836 + out];
#pragma unroll
        for (int ks = 0; ks < 32; ++ks) s += pL[(ks * 4 + key) * 128 + out];
        out0[((size_t)bs[key] * NK + rs[key]) * CH + out] = s;
    }
}

extern "C" void kernel_launch(void* const* d_in, const int* in_sizes, int n_in,
                              void* d_out, int out_size, void* d_ws, size_t ws_size,
                              hipStream_t stream)
{
    const float* fusion_feat = (const float*)d_in[0];
    const float* src_feat_a  = (const float*)d_in[1];
    const float* src_feat_b  = (const float*)d_in[2];
    const float* heat_w1 = (const float*)d_in[3];
    const float* heat_g1 = (const float*)d_in[4];
    const float* heat_b1 = (const float*)d_in[5];
    const float* heat_w2 = (const float*)d_in[6];
    const float* heat_b2 = (const float*)d_in[7];
    const float* knn_w   = (const float*)d_in[8];
    const float* knn_b   = (const float*)d_in[9];
    const float* kw_w1   = (const float*)d_in[10];
    const float* kw_g1   = (const float*)d_in[11];
    const float* kw_b1   = (const float*)d_in[12];
    const float* kw_w2   = (const float*)d_in[13];
    const float* kw_b2   = (const float*)d_in[14];
    const float* fuse_w1 = (const float*)d_in[15];
    const float* fuse_g1 = (const float*)d_in[16];
    const float* fuse_b1 = (const float*)d_in[17];
    const float* fuse_w2 = (const float*)d_in[18];
    const float* fuse_b2 = (const float*)d_in[19];
    const int* fusion_coords = (const int*)d_in[20];
    const int* src_coords_a  = (const int*)d_in[21];
    const int* src_coords_b  = (const int*)d_in[22];

    float* out = (float*)d_out;
    char* ws = (char*)d_ws;
    int* cls = (int*)(ws + WS_CLS);
    int* tki = (int*)(ws + WS_TKI);
    float* keyworld = (float*)(ws + WS_KW);
    float* mf = (float*)(ws + WS_MF);
    unsigned long long* keys = (unsigned long long*)(ws + WS_KEYS);
    int* bh = (int*)(ws + WS_BH);
    unsigned* rawk = (unsigned*)(ws + WS_RAWK);
    int* gstart = (int*)(ws + WS_GSTART);
    float2* pts = (float2*)(ws + WS_PTS);
    int* pidx = (int*)(ws + WS_PIDX);

    heat_kernel<<<(BB * NF) / 64 + 4 * GB, 256, 0, stream>>>(
        fusion_feat, heat_w1, heat_g1, heat_b1, heat_w2, heat_b2,
        out + OUT2_OFF, out + OUT3_OFF, cls, keys,
        src_coords_a, src_coords_b, bh, rawk);

    mid_kernel<<<2 + 4 * GB, 1024, 0, stream>>>(
        keys, rawk, cls, fusion_coords,
        out + OUT1_OFF, out + OUT4_OFF, tki, keyworld,
        src_coords_a, src_coords_b, bh, gstart, pts, pidx);

    knn_kernel<<<2 * BB * NK, 256, 0, stream>>>(
        src_feat_a, src_feat_b, gstart, pts, pidx,
        knn_w, knn_b, keyworld, mf);

    fuse_kernel<<<(BB * NK) / KPB, 1024, 0, stream>>>(
        fusion_feat, tki, kw_w1, kw_g1, kw_b1, kw_w2, kw_b2,
        fuse_w1, fuse_g1, fuse_b1, fuse_w2, fuse_b2, mf, out + OUT0_OFF);
}